// Round 12
// baseline (262.691 us; speedup 1.0000x reference)
//
#include <hip/hip_runtime.h>
#include <math.h>

#define D_MODEL 512
#define SEQ     2048
#define BATCH   4
#define NH      8
#define HD      64
#define CHUNK   32
#define NCHUNK  64
#define M_TOK   (BATCH*SEQ)   // 8192

typedef __attribute__((ext_vector_type(8))) short bhalf8;   // 8 bf16 = 4 VGPR
typedef __attribute__((ext_vector_type(4))) float f32x4;

__device__ __forceinline__ float sigmoidf_(float x){ return 1.f/(1.f+expf(-x)); }

__device__ __forceinline__ unsigned short f2b(float f){   // fp32 -> bf16 RNE
  unsigned u = __float_as_uint(f);
  u += 0x7FFFu + ((u>>16)&1u);
  return (unsigned short)(u>>16);
}
__device__ __forceinline__ float b2f(unsigned short h){
  return __uint_as_float(((unsigned)h)<<16);
}
__device__ __forceinline__ float blo(unsigned v){ return __uint_as_float(v<<16); }
__device__ __forceinline__ float bhi(unsigned v){ return __uint_as_float(v & 0xFFFF0000u); }
__device__ __forceinline__ unsigned bpack(float a, float b){
  return (unsigned)f2b(a) | ((unsigned)f2b(b)<<16);
}

__device__ __forceinline__ void gll16(const void* g, void* l){
  __builtin_amdgcn_global_load_lds(
      (const __attribute__((address_space(1))) unsigned int*)g,
      (__attribute__((address_space(3))) unsigned int*)l, 16, 0, 0);
}

__device__ __forceinline__ float exp2_hw(float x){
  float r;
  asm volatile("v_exp_f32 %0, %1" : "=v"(r) : "v"(x));
  return r;
}

// ---------- paired block reduction: one barrier round for two sums ----------
__device__ __forceinline__ void block_sum2(float& a, float& b, float* lds){
  #pragma unroll
  for (int o=32;o>0;o>>=1){ a += __shfl_xor(a,o); b += __shfl_xor(b,o); }
  int w = threadIdx.x>>6, l = threadIdx.x&63;
  if (l==0){ lds[2*w]=a; lds[2*w+1]=b; }
  __syncthreads();
  float ta=0.f, tb=0.f; int nw = blockDim.x>>6;
  for (int i=0;i<nw;++i){ ta+=lds[2*i]; tb+=lds[2*i+1]; }
  a=ta; b=tb;
  __syncthreads();
}

// ---------- merged: weight converts + shift (bf16 out only) ----------
__global__ void cvtshift_k(const float* __restrict__ s0,const float* __restrict__ s1,
                           const float* __restrict__ s2,const float* __restrict__ s3,
                           const float* __restrict__ s4,const float* __restrict__ s5,
                           unsigned short* __restrict__ d0,unsigned short* __restrict__ d1,
                           unsigned short* __restrict__ d2,unsigned short* __restrict__ d3,
                           unsigned short* __restrict__ d4,unsigned short* __restrict__ d5,
                           const float* __restrict__ x, const float* __restrict__ xp,
                           const float* __restrict__ mu,
                           unsigned short* __restrict__ ob){
  int t = blockIdx.x*blockDim.x + threadIdx.x;
  if (t < 917504){
    int j = t;
    const float* s; unsigned short* d;
    if (j < 196608){ s=s0; d=d0; }
    else if ((j-=196608) < 65536){ s=s1; d=d1; }
    else if ((j-=65536)  < 65536){ s=s2; d=d2; }
    else if ((j-=65536)  < 65536){ s=s3; d=d3; }
    else if ((j-=65536)  < 262144){ s=s4; d=d4; }
    else { j-=262144; s=s5; d=d5; }
    float4 v = ((const float4*)s)[j];
    uint2 p; p.x = bpack(v.x, v.y); p.y = bpack(v.z, v.w);
    ((uint2*)d)[j] = p;
  } else {
    int i = t - 917504;   // 0 .. 1048575
    float m = mu[0];
    float4 a = ((const float4*)x)[i], p = ((const float4*)xp)[i];
    float4 r;
    r.x = m*a.x + (1.f-m)*p.x; r.y = m*a.y + (1.f-m)*p.y;
    r.z = m*a.z + (1.f-m)*p.z; r.w = m*a.w + (1.f-m)*p.w;
    uint2 q; q.x = bpack(r.x, r.y); q.y = bpack(r.z, r.w);
    ((uint2*)ob)[i] = q;
  }
}

// ---------- bf16 MFMA GEMM 128x128, XCD-swizzled (unchanged) ----------
template<int ACT, int OUTB>
__global__ __launch_bounds__(256) void mgemm_k(const unsigned short* __restrict__ A,
    const unsigned short* __restrict__ W, const float* __restrict__ bias,
    float* __restrict__ Yf, unsigned short* __restrict__ Yb, int Nd, int K){
  __shared__ unsigned short As[128*64];
  __shared__ unsigned short Bs[128*64];
  const int tid = threadIdx.x;
  const int w = tid>>6, lane = tid&63;
  const int l15 = lane&15, l4 = lane>>4;
  const int wr = w>>1, wc = w&1;
  const int nwg = gridDim.x*gridDim.y;
  const int orig = blockIdx.y*gridDim.x + blockIdx.x;
  const int swz = (orig&7)*(nwg>>3) + (orig>>3);
  const int bn = swz % gridDim.x;
  const int bm = swz / gridDim.x;

  const size_t Kb = (size_t)K*2;
  const int srow  = lane>>3;
  const int sbyte = ((lane&7)*16) ^ (srow<<4);
  const char* Ag = (const char*)A + (size_t)(bm*128)*Kb + sbyte;
  const char* Wg = (const char*)W + (size_t)(bn*128)*Kb + sbyte;

  f32x4 acc[4][4];
  const f32x4 z = {0.f,0.f,0.f,0.f};
  #pragma unroll
  for (int i=0;i<4;++i)
    #pragma unroll
    for (int j=0;j<4;++j) acc[i][j] = z;

  const int KT = K/64;
  for (int kt=0; kt<KT; ++kt){
    if (kt) __syncthreads();
    const size_t kOff = (size_t)kt*128;
    #pragma unroll
    for (int i=0;i<4;++i){
      int c = w*4 + i;
      int r = c*8 + srow;
      gll16(Ag + (size_t)r*Kb + kOff, (char*)As + c*1024);
      gll16(Wg + (size_t)r*Kb + kOff, (char*)Bs + c*1024);
    }
    __syncthreads();

    bhalf8 af[4][2], bf_[4][2];
    #pragma unroll
    for (int fr=0; fr<4; ++fr){
      int row = wr*64 + fr*16 + l15;
      #pragma unroll
      for (int ks=0; ks<2; ++ks){
        int byo = (l4*16 + ks*64) ^ ((row&7)<<4);
        af[fr][ks] = *(const bhalf8*)((const char*)As + row*128 + byo);
      }
    }
    #pragma unroll
    for (int fc=0; fc<4; ++fc){
      int row = wc*64 + fc*16 + l15;
      #pragma unroll
      for (int ks=0; ks<2; ++ks){
        int byo = (l4*16 + ks*64) ^ ((row&7)<<4);
        bf_[fc][ks] = *(const bhalf8*)((const char*)Bs + row*128 + byo);
      }
    }
    #pragma unroll
    for (int ks=0; ks<2; ++ks)
      #pragma unroll
      for (int fr=0; fr<4; ++fr)
        #pragma unroll
        for (int fc=0; fc<4; ++fc)
          acc[fr][fc] = __builtin_amdgcn_mfma_f32_16x16x32_bf16(af[fr][ks], bf_[fc][ks], acc[fr][fc], 0, 0, 0);
  }

  const int rowBase = bm*128 + wr*64;
  const int colBase = bn*128 + wc*64;
  #pragma unroll
  for (int fc=0; fc<4; ++fc){
    int col = colBase + fc*16 + l15;
    float bv = bias[col];
    #pragma unroll
    for (int fr=0; fr<4; ++fr){
      #pragma unroll
      for (int j=0; j<4; ++j){
        int row = rowBase + fr*16 + l4*4 + j;
        float v = acc[fr][fc][j] + bv;
        if (ACT) v = fmaxf(v, 0.f);
        if (OUTB) Yb[(size_t)row*Nd + col] = f2b(v);
        else      Yf[(size_t)row*Nd + col] = v;
      }
    }
  }
}

// ---------- bf16 MFMA GEMM 128x64, XCD-swizzled; FUSE2 or SPLITK ----------
template<int ACT, int FUSE2, int SPLITK>
__global__ __launch_bounds__(256) void mgemm64_k(const unsigned short* __restrict__ A,
    const unsigned short* __restrict__ W0, const unsigned short* __restrict__ W1v,
    const float* __restrict__ bias0, const float* __restrict__ bias1,
    unsigned short* __restrict__ Yb0, unsigned short* __restrict__ Yb1,
    int Nd, int K){
  __shared__ unsigned short As[128*64];
  __shared__ unsigned short Bs[64*64];
  const int tid = threadIdx.x;
  const int w = tid>>6, lane = tid&63;
  const int l15 = lane&15, l4 = lane>>4;
  const int wr = w>>1, wc = w&1;
  const int nwg = gridDim.x*gridDim.y;
  const int orig = blockIdx.y*gridDim.x + blockIdx.x;
  const int swz = (orig&7)*(nwg>>3) + (orig>>3);
  int bn = swz % gridDim.x;
  const int bm = swz / gridDim.x;
  const unsigned short* W = W0;
  const float* bias = bias0;
  unsigned short* Yb = Yb0;
  int half = 0;
  if (FUSE2 && bn >= 8){ W = W1v; bias = bias1; Yb = Yb1; bn -= 8; }
  if (SPLITK && bn >= 8){ half = 1; Yb = Yb1; bn -= 8; }

  const int Ksr = SPLITK ? (K>>1) : K;          // reduction depth per block
  const size_t Kb = (size_t)K*2;                // row stride bytes
  const size_t hOff = (size_t)half * Ksr * 2;   // split-K column offset
  const int srow  = lane>>3;
  const int sbyte = ((lane&7)*16) ^ (srow<<4);
  const char* Ag = (const char*)A + (size_t)(bm*128)*Kb + hOff + sbyte;
  const char* Wg = (const char*)W + (size_t)(bn*64)*Kb + hOff + sbyte;

  f32x4 acc[4][2];
  const f32x4 z = {0.f,0.f,0.f,0.f};
  #pragma unroll
  for (int i=0;i<4;++i)
    #pragma unroll
    for (int j=0;j<2;++j) acc[i][j] = z;

  const int KT = Ksr/64;
  for (int kt=0; kt<KT; ++kt){
    if (kt) __syncthreads();
    const size_t kOff = (size_t)kt*128;
    #pragma unroll
    for (int i=0;i<4;++i){
      int c = w*4 + i;
      int r = c*8 + srow;
      gll16(Ag + (size_t)r*Kb + kOff, (char*)As + c*1024);
    }
    #pragma unroll
    for (int i=0;i<2;++i){
      int c = w*2 + i;
      int r = c*8 + srow;
      gll16(Wg + (size_t)r*Kb + kOff, (char*)Bs + c*1024);
    }
    __syncthreads();

    bhalf8 af[4][2], bf_[2][2];
    #pragma unroll
    for (int fr=0; fr<4; ++fr){
      int row = wr*64 + fr*16 + l15;
      #pragma unroll
      for (int ks=0; ks<2; ++ks){
        int byo = (l4*16 + ks*64) ^ ((row&7)<<4);
        af[fr][ks] = *(const bhalf8*)((const char*)As + row*128 + byo);
      }
    }
    #pragma unroll
    for (int fc=0; fc<2; ++fc){
      int row = wc*32 + fc*16 + l15;
      #pragma unroll
      for (int ks=0; ks<2; ++ks){
        int byo = (l4*16 + ks*64) ^ ((row&7)<<4);
        bf_[fc][ks] = *(const bhalf8*)((const char*)Bs + row*128 + byo);
      }
    }
    #pragma unroll
    for (int ks=0; ks<2; ++ks)
      #pragma unroll
      for (int fr=0; fr<4; ++fr)
        #pragma unroll
        for (int fc=0; fc<2; ++fc)
          acc[fr][fc] = __builtin_amdgcn_mfma_f32_16x16x32_bf16(af[fr][ks], bf_[fc][ks], acc[fr][fc], 0, 0, 0);
  }

  const int rowBase = bm*128 + wr*64;
  const int colBase = bn*64 + wc*32;
  #pragma unroll
  for (int fc=0; fc<2; ++fc){
    int col = colBase + fc*16 + l15;
    float bv = (SPLITK && half) ? 0.f : bias[col];
    #pragma unroll
    for (int fr=0; fr<4; ++fr){
      #pragma unroll
      for (int j=0; j<4; ++j){
        int row = rowBase + fr*16 + l4*4 + j;
        float v = acc[fr][fc][j] + bv;
        if (ACT) v = fmaxf(v, 0.f);
        Yb[(size_t)row*Nd + col] = f2b(v);
      }
    }
  }
}

// ---------- bf16 MFMA flash attention: QBLK=256, 8 waves x 2 subtiles ----------
// block = (qt, h, b), grid 256 (1/CU). Wave w owns q rows qt*256 + w*32 + t*16 + l15.
// kf/vf LDS reads shared across both subtiles (halves per-CU LDS read traffic).
__global__ __launch_bounds__(512, 2) void fattn_k(const unsigned short* __restrict__ qkv,
                                                  unsigned short* __restrict__ ao){
  __shared__ unsigned short Ks[2][64*64];
  __shared__ unsigned short Vt[2][64*64];
  __shared__ unsigned short Ps[256*64];
  const int nwg = gridDim.x*gridDim.y*gridDim.z;   // 256
  const int orig = (blockIdx.z*gridDim.y + blockIdx.y)*gridDim.x + blockIdx.x;
  const int swz = (orig&7)*(nwg>>3) + (orig>>3);
  const int qt = swz % gridDim.x;
  const int rem = swz / gridDim.x;
  const int h = rem % gridDim.y;
  const int b = rem / gridDim.y;
  const int tid = threadIdx.x, w = tid>>6, lane = tid&63;
  const int l15 = lane&15, l4 = lane>>4;
  const size_t rowB = 3072;
  const char* base = (const char*)qkv + (size_t)b*SEQ*rowB;
  const char* Kg = base + 1024 + h*128;
  const char* Vg = base + 2048 + h*128;
  const float C2 = 0.18033688f;             // 0.125 * log2(e)

  bhalf8 qf[2][2];
  #pragma unroll
  for (int t=0;t<2;++t){
    const char* qrow = base + (size_t)(qt*256 + w*32 + t*16 + l15)*rowB + h*128;
    qf[t][0] = *(const bhalf8*)(qrow + l4*16);
    qf[t][1] = *(const bhalf8*)(qrow + l4*16 + 64);
  }
  bhalf8 v1;
  {
    short o = (l15==0) ? (short)0x3F80 : (short)0;
    v1 = (bhalf8){o,o,o,o,o,o,o,o};
  }

  const f32x4 z = {0.f,0.f,0.f,0.f};
  f32x4 oa[2][4], ol[2];
  #pragma unroll
  for (int t=0;t<2;++t){
    #pragma unroll
    for (int i=0;i<4;++i) oa[t][i] = z;
    ol[t] = z;
  }
  float mj[2] = {-INFINITY, -INFINITY};

  const int srow  = lane>>3;
  const int sbyte = ((lane&7)*16) ^ (srow<<4);
  const int vd = lane;
  const int vsel = (vd>>3)&1;

  unsigned short vload[8];
  {
    int r = w*8 + srow;
    gll16(Kg + (size_t)r*rowB + sbyte, (char*)Ks[0] + w*1024);
  }
  #pragma unroll
  for (int i=0;i<8;++i)
    vload[i] = *(const unsigned short*)(Vg + (size_t)(w*8 + i)*rowB + vd*2);

  int cur = 0;
  for (int kt=0; kt<SEQ/64; ++kt){
    // write Vt[cur] from regs: 2 b64 swizzled writes, order permuted by vsel
    #pragma unroll
    for (int i=0;i<2;++i){
      int p = i ^ vsel;
      unsigned lo = (unsigned)vload[p*4+0] | ((unsigned)vload[p*4+1]<<16);
      unsigned hi = (unsigned)vload[p*4+2] | ((unsigned)vload[p*4+3]<<16);
      uint2 pk; pk.x = lo; pk.y = hi;
      int byo = (w*16 + p*8) ^ ((vd&7)<<4);
      *(uint2*)((char*)Vt[cur] + vd*128 + byo) = pk;
    }
    __syncthreads();   // Ks[cur] gll16 drained + Vt[cur] visible

    // prefetch next tile (K via gll16 into other buffer; V into regs)
    if (kt+1 < SEQ/64){
      int r = w*8 + srow;
      gll16(Kg + (size_t)((kt+1)*64 + r)*rowB + sbyte, (char*)Ks[cur^1] + w*1024);
      #pragma unroll
      for (int i=0;i<8;++i)
        vload[i] = *(const unsigned short*)(Vg + (size_t)((kt+1)*64 + w*8 + i)*rowB + vd*2);
    }

    // ---- compute from buffers [cur] ----
    // K fragments read ONCE, used by both subtiles
    bhalf8 kf[4][2];
    #pragma unroll
    for (int fc=0; fc<4; ++fc){
      int kr = fc*16 + l15;
      #pragma unroll
      for (int ks=0; ks<2; ++ks){
        int byo = (l4*16 + ks*64) ^ ((kr&7)<<4);
        kf[fc][ks] = *(const bhalf8*)((const char*)Ks[cur] + kr*128 + byo);
      }
    }

    // per-subtile: QK^T then online softmax + pack
    #pragma unroll
    for (int t=0; t<2; ++t){
      f32x4 s[4];
      #pragma unroll
      for (int i=0;i<4;++i) s[i] = z;
      __builtin_amdgcn_s_setprio(1);
      #pragma unroll
      for (int ks=0; ks<2; ++ks)
        #pragma unroll
        for (int fc=0; fc<4; ++fc)
          s[fc] = __builtin_amdgcn_mfma_f32_16x16x32_bf16(kf[fc][ks], qf[t][ks], s[fc], 0, 0, 0);
      __builtin_amdgcn_s_setprio(0);

      float rm0 = fmaxf(fmaxf(s[0][0],s[0][1]), fmaxf(s[0][2],s[0][3]));
      float rm1 = fmaxf(fmaxf(s[1][0],s[1][1]), fmaxf(s[1][2],s[1][3]));
      float rm2 = fmaxf(fmaxf(s[2][0],s[2][1]), fmaxf(s[2][2],s[2][3]));
      float rm3 = fmaxf(fmaxf(s[3][0],s[3][1]), fmaxf(s[3][2],s[3][3]));
      float rm = fmaxf(fmaxf(rm0,rm1), fmaxf(rm2,rm3));
      rm = fmaxf(rm, __shfl_xor(rm,16));
      rm = fmaxf(rm, __shfl_xor(rm,32));
      float tmax = rm * C2;
      if (__any(tmax > mj[t] + 8.f)){
        float mn = fmaxf(mj[t], tmax);
        float sc = exp2_hw(mj[t] - mn);
        mj[t] = mn;
        float scj0 = __shfl(sc, l4*4+0), scj1 = __shfl(sc, l4*4+1);
        float scj2 = __shfl(sc, l4*4+2), scj3 = __shfl(sc, l4*4+3);
        #pragma unroll
        for (int fc=0; fc<4; ++fc){
          oa[t][fc][0] *= scj0; oa[t][fc][1] *= scj1;
          oa[t][fc][2] *= scj2; oa[t][fc][3] *= scj3;
        }
        ol[t][0] *= scj0; ol[t][1] *= scj1; ol[t][2] *= scj2; ol[t][3] *= scj3;
      }
      int qrow = w*32 + t*16 + l15;
      #pragma unroll
      for (int fc=0; fc<4; ++fc){
        float p0 = exp2_hw(fmaf(C2, s[fc][0], -mj[t]));
        float p1 = exp2_hw(fmaf(C2, s[fc][1], -mj[t]));
        float p2 = exp2_hw(fmaf(C2, s[fc][2], -mj[t]));
        float p3 = exp2_hw(fmaf(C2, s[fc][3], -mj[t]));
        unsigned lo, hi;
        asm volatile("v_cvt_pk_bf16_f32 %0, %1, %2" : "=v"(lo) : "v"(p0), "v"(p1));
        asm volatile("v_cvt_pk_bf16_f32 %0, %1, %2" : "=v"(hi) : "v"(p2), "v"(p3));
        uint2 pk; pk.x = lo; pk.y = hi;
        int byo = (fc*32 + l4*8) ^ ((l15&7)<<4);
        *(uint2*)((char*)Ps + qrow*128 + byo) = pk;
      }
    }

    // V fragments read ONCE, used by both subtiles
    bhalf8 vf[4][2];
    #pragma unroll
    for (int fc=0; fc<4; ++fc){
      int d = fc*16 + l15;
      #pragma unroll
      for (int ks=0; ks<2; ++ks){
        int byo = (ks*64 + l4*16) ^ ((d&7)<<4);
        vf[fc][ks] = *(const bhalf8*)((const char*)Vt[cur] + d*128 + byo);
      }
    }
    #pragma unroll
    for (int t=0; t<2; ++t){
      int qrow = w*32 + t*16 + l15;
      bhalf8 pf[2];
      #pragma unroll
      for (int ks=0; ks<2; ++ks){
        int byo = (ks*64 + l4*16) ^ ((l15&7)<<4);
        pf[ks] = *(const bhalf8*)((const char*)Ps + qrow*128 + byo);
      }
      __builtin_amdgcn_s_setprio(1);
      #pragma unroll
      for (int ks=0; ks<2; ++ks){
        #pragma unroll
        for (int fc=0; fc<4; ++fc)
          oa[t][fc] = __builtin_amdgcn_mfma_f32_16x16x32_bf16(pf[ks], vf[fc][ks], oa[t][fc], 0, 0, 0);
        ol[t] = __builtin_amdgcn_mfma_f32_16x16x32_bf16(pf[ks], v1, ol[t], 0, 0, 0);
      }
      __builtin_amdgcn_s_setprio(0);
    }
    cur ^= 1;
  }

  // epilogue per subtile
  #pragma unroll
  for (int t=0; t<2; ++t){
    float li[4];
    #pragma unroll
    for (int j=0;j<4;++j) li[j] = 1.f/__shfl(ol[t][j], l4<<4);
    #pragma unroll
    for (int fc=0; fc<4; ++fc){
      int col = h*64 + fc*16 + l15;
      size_t r0 = (size_t)(b*SEQ + qt*256 + w*32 + t*16 + l4*4);
      ao[(r0+0)*D_MODEL + col] = f2b(oa[t][fc][0]*li[0]);
      ao[(r0+1)*D_MODEL + col] = f2b(oa[t][fc][1]*li[1]);
      ao[(r0+2)*D_MODEL + col] = f2b(oa[t][fc][2]*li[2]);
      ao[(r0+3)*D_MODEL + col] = f2b(oa[t][fc][3]*li[3]);
    }
  }
}

// ---------- final LN: out = LN(x2b + F0 + F1), all bf16 in, fp32 out ----------
__global__ __launch_bounds__(256) void lnfin_k(const unsigned int* __restrict__ X2b,
    const unsigned int* __restrict__ F0, const unsigned int* __restrict__ F1,
    const float* __restrict__ g, const float* __restrict__ be, float* __restrict__ outf){
  __shared__ float lds[16];
  const size_t off2 = (size_t)blockIdx.x * 256;
  const int tid = threadIdx.x;
  unsigned xv = X2b[off2+tid], f0 = F0[off2+tid], f1 = F1[off2+tid];
  float a0 = blo(xv) + blo(f0) + blo(f1);
  float a1 = bhi(xv) + bhi(f0) + bhi(f1);
  float s1 = a0+a1, s2 = a0*a0+a1*a1;
  block_sum2(s1, s2, lds);
  float mean = s1 * (1.f/512.f);
  float var  = s2 * (1.f/512.f) - mean*mean;
  float rstd = rsqrtf(var + 1e-5f);
  float2 gg = ((const float2*)g)[tid], bb = ((const float2*)be)[tid];
  float2 r;
  r.x = (a0-mean)*rstd*gg.x + bb.x;
  r.y = (a1-mean)*rstd*gg.y + bb.y;
  ((float2*)outf)[off2+tid] = r;
}

// ---------- fused: x1 = LN(shifted+proj); scan prep; all bf16 I/O ----------
__global__ __launch_bounds__(256) void ln_scan_k(const unsigned int* __restrict__ Ab,
    const unsigned int* __restrict__ Pb,
    const float* __restrict__ g, const float* __restrict__ be, const float* __restrict__ tm,
    unsigned int* __restrict__ x1b, unsigned int* __restrict__ dec, unsigned int* __restrict__ u,
    float* __restrict__ dm, float* __restrict__ es){
  __shared__ float lds[16];
  const size_t row = blockIdx.x;
  const size_t off2 = row * 256;
  const int tid = threadIdx.x;
  unsigned av = Ab[off2+tid], pv = Pb[off2+tid];
  float a0 = blo(av) + blo(pv);
  float a1 = bhi(av) + bhi(pv);
  float s1 = a0+a1, s2 = a0*a0+a1*a1;
  block_sum2(s1, s2, lds);
  float mean = s1 * (1.f/512.f);
  float var  = s2 * (1.f/512.f) - mean*mean;
  float rstd = rsqrtf(var + 1e-5f);
  float2 gg = ((const float2*)g)[tid], bb = ((const float2*)be)[tid], tt = ((const float2*)tm)[tid];
  float r0 = (a0-mean)*rstd*gg.x + bb.x;
  float r1 = (a1-mean)*rstd*gg.y + bb.y;
  x1b[off2+tid] = bpack(r0, r1);
  float dc0 = sigmoidf_(r0*tt.x), dc1 = sigmoidf_(r1*tt.y);
  float e0 = expf(r0), e1 = expf(r1);
  dec[off2+tid] = bpack(dc0, dc1);
  u[off2+tid]   = bpack(e0*r0, e1*r1);
  float dsum = dc0+dc1, esum = e0+e1;
  block_sum2(dsum, esum, lds);
  if (tid==0){ dm[row]=dsum*(1.f/512.f); es[row]=esum; }
}

// ---------- fused: coupled = LN(sigmoid(R)*V); x2 = LN(X1+coupled); bf16 I/O ----------
__global__ __launch_bounds__(256) void ln2x_k(const unsigned int* __restrict__ R,
    const unsigned int* __restrict__ V, const unsigned int* __restrict__ X1,
    const float* __restrict__ g1, const float* __restrict__ b1_,
    const float* __restrict__ g2, const float* __restrict__ b2_,
    unsigned int* __restrict__ x2b){
  __shared__ float lds[16];
  const size_t off2 = (size_t)blockIdx.x * 256;
  const int tid = threadIdx.x;
  unsigned rv = R[off2+tid], vv = V[off2+tid];
  float a0 = sigmoidf_(blo(rv))*blo(vv);
  float a1 = sigmoidf_(bhi(rv))*bhi(vv);
  float s1 = a0+a1, s2 = a0*a0+a1*a1;
  block_sum2(s1, s2, lds);
  float mean = s1*(1.f/512.f);
  float var  = s2*(1.f/512.f) - mean*mean;
  float rstd = rsqrtf(var + 1e-5f);
  float2 g1v = ((const float2*)g1)[tid], b1v = ((const float2*)b1_)[tid];
  float c0 = (a0-mean)*rstd*g1v.x + b1v.x;
  float c1 = (a1-mean)*rstd*g1v.y + b1v.y;
  unsigned x1v = X1[off2+tid];
  float t0 = blo(x1v) + c0, t1 = bhi(x1v) + c1;
  float u1 = t0+t1, u2 = t0*t0+t1*t1;
  block_sum2(u1, u2, lds);
  float mean2 = u1*(1.f/512.f);
  float var2  = u2*(1.f/512.f) - mean2*mean2;
  float rstd2 = rsqrtf(var2 + 1e-5f);
  float2 g2v = ((const float2*)g2)[tid], b2v = ((const float2*)b2_)[tid];
  float r0 = (t0-mean2)*rstd2*g2v.x + b2v.x;
  float r1 = (t1-mean2)*rstd2*g2v.y + b2v.y;
  x2b[off2+tid] = bpack(r0, r1);
}

// ---------- b scan phase 1 (bf16 in, 256 threads, paired) ----------
__global__ __launch_bounds__(256) void bscan_p1(const unsigned int* __restrict__ decay,
    const unsigned int* __restrict__ u, float* __restrict__ Gc, float* __restrict__ Uc){
  const int c = blockIdx.x, b = blockIdx.y, t = threadIdx.x;
  size_t base2 = ((size_t)b*SEQ + (size_t)c*CHUNK)*256 + t;
  float G0=1.f, G1=1.f, U0=0.f, U1=0.f;
  for (int i=0;i<CHUNK;++i){
    unsigned dv = decay[base2 + (size_t)i*256];
    unsigned uv = u[base2 + (size_t)i*256];
    float g0 = blo(dv), g1 = bhi(dv);
    U0 = g0*U0 + blo(uv); G0 *= g0;
    U1 = g1*U1 + bhi(uv); G1 *= g1;
  }
  size_t idx2 = ((size_t)b*NCHUNK + c)*256 + t;
  float2 gv; gv.x=G0; gv.y=G1;
  float2 uv2; uv2.x=U0; uv2.y=U1;
  ((float2*)Gc)[idx2] = gv;
  ((float2*)Uc)[idx2] = uv2;
}

// ---------- merged: b-scan phase 2 (blocks 0-3) + 'a' scan (blocks 4-7) ----------
__global__ __launch_bounds__(512) void scan2_k(const float* __restrict__ Gc, const float* __restrict__ Uc,
    float* __restrict__ binit, const float* __restrict__ dm, const float* __restrict__ es,
    float* __restrict__ a_out){
  __shared__ float sG[512], sU[512];
  if (blockIdx.x < 4){
    const int b = blockIdx.x, d = threadIdx.x;
    float cur = 0.f;
    for (int c=0;c<NCHUNK;++c){
      size_t idx = ((size_t)b*NCHUNK + c)*D_MODEL + d;
      binit[idx] = cur;
      cur = Gc[idx]*cur + Uc[idx];
    }
  } else {
    const int b = blockIdx.x - 4, tid = threadIdx.x;
    const float* dmb = dm + (size_t)b*SEQ;
    const float* esb = es + (size_t)b*SEQ;
    const int t0 = tid*4;
    float gi[4], ui[4];
    #pragma unroll
    for (int i=0;i<4;++i){ gi[i]=dmb[t0+i]; ui[i]=esb[t0+i]; }
    float G=1.f, U=0.f;
    #pragma unroll
    for (int i=0;i<4;++i){ U = gi[i]*U + ui[i]; G *= gi[i]; }
    sG[tid]=G; sU[tid]=U;
    __syncthreads();
    for (int off=1; off<512; off<<=1){
      float pg=1.f, pu=0.f;
      bool act = tid >= off;
      if (act){ pg = sG[tid-off]; pu = sU[tid-off]; }
      __syncthreads();
      if (act){ sU[tid] = sG[tid]*pu + sU[tid]; sG[tid] = sG[tid]*pg; }
      __syncthreads();
    }
    float a = (tid==0) ? 0.f : sU[tid-1];
    #pragma unroll
    for (int i=0;i<4;++i){ a = gi[i]*a + ui[i]; a_out[(size_t)b*SEQ + t0 + i] = a; }
  }
}

// ---------- fused p3 + LN(merged), bf16 I/O, 256 threads paired ----------
__global__ __launch_bounds__(256) void p3ln_k(const unsigned int* __restrict__ decay,
    const unsigned int* __restrict__ u,
    const float* __restrict__ binit, const float* __restrict__ a,
    const float* __restrict__ g, const float* __restrict__ be,
    unsigned int* __restrict__ mb){
  __shared__ float lds[16];
  const int c = blockIdx.x, b = blockIdx.y, t = threadIdx.x;
  size_t base2 = ((size_t)b*SEQ + (size_t)c*CHUNK)*256 + t;
  float2 bv = ((const float2*)binit)[((size_t)b*NCHUNK + c)*256 + t];
  float2 gg = ((const float2*)g)[t], bb = ((const float2*)be)[t];
  for (int i=0;i<CHUNK;++i){
    unsigned dv = decay[base2 + (size_t)i*256];
    unsigned uv = u[base2 + (size_t)i*256];
    bv.x = blo(dv)*bv.x + blo(uv);
    bv.y = bhi(dv)*bv.y + bhi(uv);
    float av = a[(size_t)b*SEQ + (size_t)c*CHUNK + i];
    float inv = 1.f/(av + 1e-8f);
    float v0 = bv.x*inv, v1 = bv.y*inv;
    float s1 = v0+v1, s2 = v0*v0+v1*v1;
    block_sum2(s1, s2, lds);
    float mean = s1*(1.f/512.f);
    float var  = s2*(1.f/512.f) - mean*mean;
    float rstd = rsqrtf(var + 1e-5f);
    mb[base2 + (size_t)i*256] = bpack((v0-mean)*rstd*gg.x + bb.x,
                                      (v1-mean)*rstd*gg.y + bb.y);
  }
}

extern "C" void kernel_launch(void* const* d_in, const int* in_sizes, int n_in,
                              void* d_out, int out_size, void* d_ws, size_t ws_size,
                              hipStream_t stream){
  const float* x     = (const float*)d_in[0];
  const float* xp    = (const float*)d_in[1];
  const float* mu    = (const float*)d_in[2];
  const float* in_w  = (const float*)d_in[3];
  const float* in_b  = (const float*)d_in[4];
  const float* out_w = (const float*)d_in[5];
  const float* out_b = (const float*)d_in[6];
  const float* ln1_g = (const float*)d_in[7];
  const float* ln1_b = (const float*)d_in[8];
  const float* tm    = (const float*)d_in[9];
  const float* sm_g  = (const float*)d_in[10];
  const float* sm_b  = (const float*)d_in[11];
  const float* wr_w  = (const float*)d_in[12];
  const float* wr_b  = (const float*)d_in[13];
  const float* wv_w  = (const float*)d_in[14];
  const float* wv_b  = (const float*)d_in[15];
  const float* sc_g  = (const float*)d_in[16];
  const float* sc_b  = (const float*)d_in[17];
  const float* ln2_g = (const float*)d_in[18];
  const float* ln2_b = (const float*)d_in[19];
  const float* w1    = (const float*)d_in[20];
  const float* b1    = (const float*)d_in[21];
  const float* w2    = (const float*)d_in[22];
  const float* b2    = (const float*)d_in[23];
  const float* ln3_g = (const float*)d_in[24];
  const float* ln3_b = (const float*)d_in[25];
  float* out = (float*)d_out;
  float* ws  = (float*)d_ws;

  const size_t N = (size_t)M_TOK*D_MODEL;   // 4,194,304
  unsigned short* Pb  = (unsigned short*)ws;          // proj bf16 (8MB)
  unsigned short* X1b = (unsigned short*)ws + N;      // x1 bf16 (8MB)
  unsigned short* F0  = (unsigned short*)(ws + N);    // ffn2 half0 (8MB)
  unsigned short* F1  = (unsigned short*)(ws + N) + N;// ffn2 half1 (8MB)
  float* EX  = ws + 3*N;
  float* dm    = EX;
  float* es    = EX + 8192;
  float* aarr  = EX + 16384;
  float* Gc    = EX + 24576;
  float* Uc    = Gc + 131072;
  float* binit = Uc + 131072;

  unsigned short* SB = (unsigned short*)(ws + 3*N + N/4);
  unsigned short* Wq = SB;
  unsigned short* Wo = Wq + 786432;
  unsigned short* Wr = Wo + 262144;
  unsigned short* Wv = Wr + 262144;
  unsigned short* W1 = Wv + 262144;
  unsigned short* W2 = W1 + 1048576;
  unsigned short* Xb = W2 + 1048576;       // shifted bf16, later x2 bf16
  unsigned short* Mb = Xb + N;             // merged bf16
  unsigned short* U  = Mb + N;
  unsigned short* Qb  = U;                 // qkv bf16 (24MB)
  unsigned short* AOb = U + 12*1024*1024;  // attn out bf16 (8MB)
  unsigned short* ub   = U;                // after Qb dead
  unsigned short* decb = U + 12*1024*1024; // after AOb dead
  unsigned short* Rb   = U;                // after ub dead
  unsigned short* Vb   = U + 4*1024*1024;
  unsigned short* Hb   = U;                // FFN hidden (32MB)

  // 0. weight converts + shift (bf16 only)
  cvtshift_k<<<7680, 256, 0, stream>>>(in_w, out_w, wr_w, wv_w, w1, w2,
                                       Wq, Wo, Wr, Wv, W1, W2,
                                       x, xp, mu, Xb);
  // 1. qkv -> Qb
  mgemm_k<0,1><<<dim3(12,64), 256, 0, stream>>>(Xb, Wq, in_b, nullptr, Qb, 1536, 512);
  // 2. flash attention -> AOb (QBLK=256, grid 256, 8 waves x 2 subtiles)
  fattn_k<<<dim3(SEQ/256, NH, BATCH), 512, 0, stream>>>(Qb, AOb);
  // 3. out-proj -> Pb (bf16)
  mgemm64_k<0,0,0><<<dim3(8,64), 256, 0, stream>>>(AOb, Wo, nullptr, out_b, nullptr,
                                                   Pb, nullptr, 512, 512);
  // 4. x1 = LN(shifted+proj) -> X1b; decb/ub; dm/es
  ln_scan_k<<<M_TOK, 256, 0, stream>>>((const unsigned int*)Xb, (const unsigned int*)Pb,
                                       ln1_g, ln1_b, tm,
                                       (unsigned int*)X1b, (unsigned int*)decb, (unsigned int*)ub,
                                       dm, es);
  // 5. b-scan phase 1
  bscan_p1<<<dim3(NCHUNK, BATCH), 256, 0, stream>>>((const unsigned int*)decb, (const unsigned int*)ub, Gc, Uc);
  // 6. merged p2 + ascan
  scan2_k<<<8, 512, 0, stream>>>(Gc, Uc, binit, dm, es, aarr);
  // 7. p3 + LN(merged) -> Mb
  p3ln_k<<<dim3(NCHUNK, BATCH), 256, 0, stream>>>((const unsigned int*)decb, (const unsigned int*)ub,
                                                  binit, aarr, sm_g, sm_b, (unsigned int*)Mb);
  // 8. r -> Rb, v -> Vb (bf16, fused)
  mgemm64_k<0,1,0><<<dim3(16,64), 256, 0, stream>>>(Mb, Wr, Wv, wr_b, wv_b,
                                                    Rb, Vb, 512, 512);
  // 9. coupled-LN + x2-LN -> Xb (x2 bf16)
  ln2x_k<<<M_TOK, 256, 0, stream>>>((const unsigned int*)Rb, (const unsigned int*)Vb,
                                    (const unsigned int*)X1b,
                                    sc_g, sc_b, ln2_g, ln2_b, (unsigned int*)Xb);
  // 10. hidden = relu(x2 @ w1.T + b1) -> Hb
  mgemm_k<1,1><<<dim3(16,64), 256, 0, stream>>>(Xb, W1, b1, nullptr, Hb, 2048, 512);
  // 11. ffnout split-K -> F0 (bias) + F1
  mgemm64_k<0,0,1><<<dim3(16,64), 256, 0, stream>>>(Hb, W2, nullptr, b2, nullptr,
                                                    F0, F1, 512, 2048);
  // 12. out = LN(x2 + F0 + F1)
  lnfin_k<<<M_TOK, 256, 0, stream>>>((const unsigned int*)Xb, (const unsigned int*)F0,
                                     (const unsigned int*)F1, ln3_g, ln3_b, out);
}

// Round 13
// 251.045 us; speedup vs baseline: 1.0464x; 1.0464x over previous
//
#include <hip/hip_runtime.h>
#include <math.h>

#define D_MODEL 512
#define SEQ     2048
#define BATCH   4
#define NH      8
#define HD      64
#define CHUNK   32
#define NCHUNK  64
#define M_TOK   (BATCH*SEQ)   // 8192

typedef __attribute__((ext_vector_type(8))) short bhalf8;   // 8 bf16 = 4 VGPR
typedef __attribute__((ext_vector_type(4))) float f32x4;

__device__ __forceinline__ float sigmoidf_(float x){ return 1.f/(1.f+expf(-x)); }

__device__ __forceinline__ unsigned short f2b(float f){   // fp32 -> bf16 RNE
  unsigned u = __float_as_uint(f);
  u += 0x7FFFu + ((u>>16)&1u);
  return (unsigned short)(u>>16);
}
__device__ __forceinline__ float b2f(unsigned short h){
  return __uint_as_float(((unsigned)h)<<16);
}
__device__ __forceinline__ float blo(unsigned v){ return __uint_as_float(v<<16); }
__device__ __forceinline__ float bhi(unsigned v){ return __uint_as_float(v & 0xFFFF0000u); }
__device__ __forceinline__ unsigned bpack(float a, float b){
  return (unsigned)f2b(a) | ((unsigned)f2b(b)<<16);
}

__device__ __forceinline__ void gll16(const void* g, void* l){
  __builtin_amdgcn_global_load_lds(
      (const __attribute__((address_space(1))) unsigned int*)g,
      (__attribute__((address_space(3))) unsigned int*)l, 16, 0, 0);
}

__device__ __forceinline__ float exp2_hw(float x){
  float r;
  asm volatile("v_exp_f32 %0, %1" : "=v"(r) : "v"(x));
  return r;
}

// ---------- paired block reduction: one barrier round for two sums ----------
__device__ __forceinline__ void block_sum2(float& a, float& b, float* lds){
  #pragma unroll
  for (int o=32;o>0;o>>=1){ a += __shfl_xor(a,o); b += __shfl_xor(b,o); }
  int w = threadIdx.x>>6, l = threadIdx.x&63;
  if (l==0){ lds[2*w]=a; lds[2*w+1]=b; }
  __syncthreads();
  float ta=0.f, tb=0.f; int nw = blockDim.x>>6;
  for (int i=0;i<nw;++i){ ta+=lds[2*i]; tb+=lds[2*i+1]; }
  a=ta; b=tb;
  __syncthreads();
}

// ---------- merged: weight converts + shift (bf16 out only) ----------
__global__ void cvtshift_k(const float* __restrict__ s0,const float* __restrict__ s1,
                           const float* __restrict__ s2,const float* __restrict__ s3,
                           const float* __restrict__ s4,const float* __restrict__ s5,
                           unsigned short* __restrict__ d0,unsigned short* __restrict__ d1,
                           unsigned short* __restrict__ d2,unsigned short* __restrict__ d3,
                           unsigned short* __restrict__ d4,unsigned short* __restrict__ d5,
                           const float* __restrict__ x, const float* __restrict__ xp,
                           const float* __restrict__ mu,
                           unsigned short* __restrict__ ob){
  int t = blockIdx.x*blockDim.x + threadIdx.x;
  if (t < 917504){
    int j = t;
    const float* s; unsigned short* d;
    if (j < 196608){ s=s0; d=d0; }
    else if ((j-=196608) < 65536){ s=s1; d=d1; }
    else if ((j-=65536)  < 65536){ s=s2; d=d2; }
    else if ((j-=65536)  < 65536){ s=s3; d=d3; }
    else if ((j-=65536)  < 262144){ s=s4; d=d4; }
    else { j-=262144; s=s5; d=d5; }
    float4 v = ((const float4*)s)[j];
    uint2 p; p.x = bpack(v.x, v.y); p.y = bpack(v.z, v.w);
    ((uint2*)d)[j] = p;
  } else {
    int i = t - 917504;   // 0 .. 1048575
    float m = mu[0];
    float4 a = ((const float4*)x)[i], p = ((const float4*)xp)[i];
    float4 r;
    r.x = m*a.x + (1.f-m)*p.x; r.y = m*a.y + (1.f-m)*p.y;
    r.z = m*a.z + (1.f-m)*p.z; r.w = m*a.w + (1.f-m)*p.w;
    uint2 q; q.x = bpack(r.x, r.y); q.y = bpack(r.z, r.w);
    ((uint2*)ob)[i] = q;
  }
}

// ---------- bf16 MFMA GEMM 128x128, XCD-swizzled ----------
template<int ACT, int OUTB>
__global__ __launch_bounds__(256) void mgemm_k(const unsigned short* __restrict__ A,
    const unsigned short* __restrict__ W, const float* __restrict__ bias,
    float* __restrict__ Yf, unsigned short* __restrict__ Yb, int Nd, int K){
  __shared__ unsigned short As[128*64];
  __shared__ unsigned short Bs[128*64];
  const int tid = threadIdx.x;
  const int w = tid>>6, lane = tid&63;
  const int l15 = lane&15, l4 = lane>>4;
  const int wr = w>>1, wc = w&1;
  const int nwg = gridDim.x*gridDim.y;
  const int orig = blockIdx.y*gridDim.x + blockIdx.x;
  const int swz = (orig&7)*(nwg>>3) + (orig>>3);
  const int bn = swz % gridDim.x;
  const int bm = swz / gridDim.x;

  const size_t Kb = (size_t)K*2;
  const int srow  = lane>>3;
  const int sbyte = ((lane&7)*16) ^ (srow<<4);
  const char* Ag = (const char*)A + (size_t)(bm*128)*Kb + sbyte;
  const char* Wg = (const char*)W + (size_t)(bn*128)*Kb + sbyte;

  f32x4 acc[4][4];
  const f32x4 z = {0.f,0.f,0.f,0.f};
  #pragma unroll
  for (int i=0;i<4;++i)
    #pragma unroll
    for (int j=0;j<4;++j) acc[i][j] = z;

  const int KT = K/64;
  for (int kt=0; kt<KT; ++kt){
    if (kt) __syncthreads();
    const size_t kOff = (size_t)kt*128;
    #pragma unroll
    for (int i=0;i<4;++i){
      int c = w*4 + i;
      int r = c*8 + srow;
      gll16(Ag + (size_t)r*Kb + kOff, (char*)As + c*1024);
      gll16(Wg + (size_t)r*Kb + kOff, (char*)Bs + c*1024);
    }
    __syncthreads();

    bhalf8 af[4][2], bf_[4][2];
    #pragma unroll
    for (int fr=0; fr<4; ++fr){
      int row = wr*64 + fr*16 + l15;
      #pragma unroll
      for (int ks=0; ks<2; ++ks){
        int byo = (l4*16 + ks*64) ^ ((row&7)<<4);
        af[fr][ks] = *(const bhalf8*)((const char*)As + row*128 + byo);
      }
    }
    #pragma unroll
    for (int fc=0; fc<4; ++fc){
      int row = wc*64 + fc*16 + l15;
      #pragma unroll
      for (int ks=0; ks<2; ++ks){
        int byo = (l4*16 + ks*64) ^ ((row&7)<<4);
        bf_[fc][ks] = *(const bhalf8*)((const char*)Bs + row*128 + byo);
      }
    }
    #pragma unroll
    for (int ks=0; ks<2; ++ks)
      #pragma unroll
      for (int fr=0; fr<4; ++fr)
        #pragma unroll
        for (int fc=0; fc<4; ++fc)
          acc[fr][fc] = __builtin_amdgcn_mfma_f32_16x16x32_bf16(af[fr][ks], bf_[fc][ks], acc[fr][fc], 0, 0, 0);
  }

  const int rowBase = bm*128 + wr*64;
  const int colBase = bn*128 + wc*64;
  #pragma unroll
  for (int fc=0; fc<4; ++fc){
    int col = colBase + fc*16 + l15;
    float bv = bias[col];
    #pragma unroll
    for (int fr=0; fr<4; ++fr){
      #pragma unroll
      for (int j=0; j<4; ++j){
        int row = rowBase + fr*16 + l4*4 + j;
        float v = acc[fr][fc][j] + bv;
        if (ACT) v = fmaxf(v, 0.f);
        if (OUTB) Yb[(size_t)row*Nd + col] = f2b(v);
        else      Yf[(size_t)row*Nd + col] = v;
      }
    }
  }
}

// ---------- bf16 MFMA GEMM 128x64, XCD-swizzled; FUSE2 or SPLITK ----------
template<int ACT, int FUSE2, int SPLITK>
__global__ __launch_bounds__(256) void mgemm64_k(const unsigned short* __restrict__ A,
    const unsigned short* __restrict__ W0, const unsigned short* __restrict__ W1v,
    const float* __restrict__ bias0, const float* __restrict__ bias1,
    unsigned short* __restrict__ Yb0, unsigned short* __restrict__ Yb1,
    int Nd, int K){
  __shared__ unsigned short As[128*64];
  __shared__ unsigned short Bs[64*64];
  const int tid = threadIdx.x;
  const int w = tid>>6, lane = tid&63;
  const int l15 = lane&15, l4 = lane>>4;
  const int wr = w>>1, wc = w&1;
  const int nwg = gridDim.x*gridDim.y;
  const int orig = blockIdx.y*gridDim.x + blockIdx.x;
  const int swz = (orig&7)*(nwg>>3) + (orig>>3);
  int bn = swz % gridDim.x;
  const int bm = swz / gridDim.x;
  const unsigned short* W = W0;
  const float* bias = bias0;
  unsigned short* Yb = Yb0;
  int half = 0;
  if (FUSE2 && bn >= 8){ W = W1v; bias = bias1; Yb = Yb1; bn -= 8; }
  if (SPLITK && bn >= 8){ half = 1; Yb = Yb1; bn -= 8; }

  const int Ksr = SPLITK ? (K>>1) : K;          // reduction depth per block
  const size_t Kb = (size_t)K*2;                // row stride bytes
  const size_t hOff = (size_t)half * Ksr * 2;   // split-K column offset
  const int srow  = lane>>3;
  const int sbyte = ((lane&7)*16) ^ (srow<<4);
  const char* Ag = (const char*)A + (size_t)(bm*128)*Kb + hOff + sbyte;
  const char* Wg = (const char*)W + (size_t)(bn*64)*Kb + hOff + sbyte;

  f32x4 acc[4][2];
  const f32x4 z = {0.f,0.f,0.f,0.f};
  #pragma unroll
  for (int i=0;i<4;++i)
    #pragma unroll
    for (int j=0;j<2;++j) acc[i][j] = z;

  const int KT = Ksr/64;
  for (int kt=0; kt<KT; ++kt){
    if (kt) __syncthreads();
    const size_t kOff = (size_t)kt*128;
    #pragma unroll
    for (int i=0;i<4;++i){
      int c = w*4 + i;
      int r = c*8 + srow;
      gll16(Ag + (size_t)r*Kb + kOff, (char*)As + c*1024);
    }
    #pragma unroll
    for (int i=0;i<2;++i){
      int c = w*2 + i;
      int r = c*8 + srow;
      gll16(Wg + (size_t)r*Kb + kOff, (char*)Bs + c*1024);
    }
    __syncthreads();

    bhalf8 af[4][2], bf_[2][2];
    #pragma unroll
    for (int fr=0; fr<4; ++fr){
      int row = wr*64 + fr*16 + l15;
      #pragma unroll
      for (int ks=0; ks<2; ++ks){
        int byo = (l4*16 + ks*64) ^ ((row&7)<<4);
        af[fr][ks] = *(const bhalf8*)((const char*)As + row*128 + byo);
      }
    }
    #pragma unroll
    for (int fc=0; fc<2; ++fc){
      int row = wc*32 + fc*16 + l15;
      #pragma unroll
      for (int ks=0; ks<2; ++ks){
        int byo = (l4*16 + ks*64) ^ ((row&7)<<4);
        bf_[fc][ks] = *(const bhalf8*)((const char*)Bs + row*128 + byo);
      }
    }
    #pragma unroll
    for (int ks=0; ks<2; ++ks)
      #pragma unroll
      for (int fr=0; fr<4; ++fr)
        #pragma unroll
        for (int fc=0; fc<2; ++fc)
          acc[fr][fc] = __builtin_amdgcn_mfma_f32_16x16x32_bf16(af[fr][ks], bf_[fc][ks], acc[fr][fc], 0, 0, 0);
  }

  const int rowBase = bm*128 + wr*64;
  const int colBase = bn*64 + wc*32;
  #pragma unroll
  for (int fc=0; fc<2; ++fc){
    int col = colBase + fc*16 + l15;
    float bv = (SPLITK && half) ? 0.f : bias[col];
    #pragma unroll
    for (int fr=0; fr<4; ++fr){
      #pragma unroll
      for (int j=0; j<4; ++j){
        int row = rowBase + fr*16 + l4*4 + j;
        float v = acc[fr][fc][j] + bv;
        if (ACT) v = fmaxf(v, 0.f);
        Yb[(size_t)row*Nd + col] = f2b(v);
      }
    }
  }
}

// ---------- bf16 MFMA flash attention (R11 version — known-good 71us) ----------
__global__ __launch_bounds__(512, 4) void fattn_k(const unsigned short* __restrict__ qkv,
                                                  unsigned short* __restrict__ ao){
  __shared__ unsigned short Ks[2][64*64];
  __shared__ unsigned short Vt[2][64*64];
  __shared__ unsigned short Ps[128*64];
  const int nwg = gridDim.x*gridDim.y*gridDim.z;   // 512
  const int orig = (blockIdx.z*gridDim.y + blockIdx.y)*gridDim.x + blockIdx.x;
  const int swz = (orig&7)*(nwg>>3) + (orig>>3);
  const int qt = swz % gridDim.x;
  const int rem = swz / gridDim.x;
  const int h = rem % gridDim.y;
  const int b = rem / gridDim.y;
  const int tid = threadIdx.x, w = tid>>6, lane = tid&63;
  const int l15 = lane&15, l4 = lane>>4;
  const size_t rowB = 3072;
  const char* base = (const char*)qkv + (size_t)b*SEQ*rowB;
  const char* Kg = base + 1024 + h*128;
  const char* Vg = base + 2048 + h*128;
  const float C2 = 0.18033688f;             // 0.125 * log2(e)

  bhalf8 qf[2];
  {
    const char* qrow = base + (size_t)(qt*128 + w*16 + l15)*rowB + h*128;
    qf[0] = *(const bhalf8*)(qrow + l4*16);
    qf[1] = *(const bhalf8*)(qrow + l4*16 + 64);
  }
  bhalf8 v1;
  {
    short o = (l15==0) ? (short)0x3F80 : (short)0;
    v1 = (bhalf8){o,o,o,o,o,o,o,o};
  }

  const f32x4 z = {0.f,0.f,0.f,0.f};
  f32x4 oa[4], ol = z;
  #pragma unroll
  for (int i=0;i<4;++i) oa[i] = z;
  float mj = -INFINITY;

  const int srow  = lane>>3;
  const int sbyte = ((lane&7)*16) ^ (srow<<4);
  const int vd = lane;
  const int vsel = (vd>>3)&1;

  unsigned short vload[8];
  {
    int r = w*8 + srow;
    gll16(Kg + (size_t)r*rowB + sbyte, (char*)Ks[0] + w*1024);
  }
  #pragma unroll
  for (int i=0;i<8;++i)
    vload[i] = *(const unsigned short*)(Vg + (size_t)(w*8 + i)*rowB + vd*2);

  int cur = 0;
  for (int kt=0; kt<SEQ/64; ++kt){
    #pragma unroll
    for (int i=0;i<2;++i){
      int p = i ^ vsel;
      unsigned lo = (unsigned)vload[p*4+0] | ((unsigned)vload[p*4+1]<<16);
      unsigned hi = (unsigned)vload[p*4+2] | ((unsigned)vload[p*4+3]<<16);
      uint2 pk; pk.x = lo; pk.y = hi;
      int byo = (w*16 + p*8) ^ ((vd&7)<<4);
      *(uint2*)((char*)Vt[cur] + vd*128 + byo) = pk;
    }
    __syncthreads();

    if (kt+1 < SEQ/64){
      int r = w*8 + srow;
      gll16(Kg + (size_t)((kt+1)*64 + r)*rowB + sbyte, (char*)Ks[cur^1] + w*1024);
      #pragma unroll
      for (int i=0;i<8;++i)
        vload[i] = *(const unsigned short*)(Vg + (size_t)((kt+1)*64 + w*8 + i)*rowB + vd*2);
    }

    bhalf8 kf[4][2];
    #pragma unroll
    for (int fc=0; fc<4; ++fc){
      int kr = fc*16 + l15;
      #pragma unroll
      for (int ks=0; ks<2; ++ks){
        int byo = (l4*16 + ks*64) ^ ((kr&7)<<4);
        kf[fc][ks] = *(const bhalf8*)((const char*)Ks[cur] + kr*128 + byo);
      }
    }
    f32x4 s[4];
    #pragma unroll
    for (int i=0;i<4;++i) s[i] = z;
    __builtin_amdgcn_s_setprio(1);
    #pragma unroll
    for (int ks=0; ks<2; ++ks)
      #pragma unroll
      for (int fc=0; fc<4; ++fc)
        s[fc] = __builtin_amdgcn_mfma_f32_16x16x32_bf16(kf[fc][ks], qf[ks], s[fc], 0, 0, 0);
    __builtin_amdgcn_s_setprio(0);

    {
      float rm0 = fmaxf(fmaxf(s[0][0],s[0][1]), fmaxf(s[0][2],s[0][3]));
      float rm1 = fmaxf(fmaxf(s[1][0],s[1][1]), fmaxf(s[1][2],s[1][3]));
      float rm2 = fmaxf(fmaxf(s[2][0],s[2][1]), fmaxf(s[2][2],s[2][3]));
      float rm3 = fmaxf(fmaxf(s[3][0],s[3][1]), fmaxf(s[3][2],s[3][3]));
      float rm = fmaxf(fmaxf(rm0,rm1), fmaxf(rm2,rm3));
      rm = fmaxf(rm, __shfl_xor(rm,16));
      rm = fmaxf(rm, __shfl_xor(rm,32));
      float tmax = rm * C2;
      if (__any(tmax > mj + 8.f)){
        float mn = fmaxf(mj, tmax);
        float sc = exp2_hw(mj - mn);
        mj = mn;
        float scj0 = __shfl(sc, l4*4+0), scj1 = __shfl(sc, l4*4+1);
        float scj2 = __shfl(sc, l4*4+2), scj3 = __shfl(sc, l4*4+3);
        #pragma unroll
        for (int fc=0; fc<4; ++fc){
          oa[fc][0] *= scj0; oa[fc][1] *= scj1;
          oa[fc][2] *= scj2; oa[fc][3] *= scj3;
        }
        ol[0] *= scj0; ol[1] *= scj1; ol[2] *= scj2; ol[3] *= scj3;
      }
      int qrow = w*16 + l15;
      #pragma unroll
      for (int fc=0; fc<4; ++fc){
        float p0 = exp2_hw(fmaf(C2, s[fc][0], -mj));
        float p1 = exp2_hw(fmaf(C2, s[fc][1], -mj));
        float p2 = exp2_hw(fmaf(C2, s[fc][2], -mj));
        float p3 = exp2_hw(fmaf(C2, s[fc][3], -mj));
        unsigned lo, hi;
        asm volatile("v_cvt_pk_bf16_f32 %0, %1, %2" : "=v"(lo) : "v"(p0), "v"(p1));
        asm volatile("v_cvt_pk_bf16_f32 %0, %1, %2" : "=v"(hi) : "v"(p2), "v"(p3));
        uint2 pk; pk.x = lo; pk.y = hi;
        int byo = (fc*32 + l4*8) ^ ((l15&7)<<4);
        *(uint2*)((char*)Ps + qrow*128 + byo) = pk;
      }
    }

    bhalf8 vf[4][2];
    #pragma unroll
    for (int fc=0; fc<4; ++fc){
      int d = fc*16 + l15;
      #pragma unroll
      for (int ks=0; ks<2; ++ks){
        int byo = (ks*64 + l4*16) ^ ((d&7)<<4);
        vf[fc][ks] = *(const bhalf8*)((const char*)Vt[cur] + d*128 + byo);
      }
    }
    {
      int qrow = w*16 + l15;
      bhalf8 pf[2];
      #pragma unroll
      for (int ks=0; ks<2; ++ks){
        int byo = (ks*64 + l4*16) ^ ((l15&7)<<4);
        pf[ks] = *(const bhalf8*)((const char*)Ps + qrow*128 + byo);
      }
      __builtin_amdgcn_s_setprio(1);
      #pragma unroll
      for (int ks=0; ks<2; ++ks){
        #pragma unroll
        for (int fc=0; fc<4; ++fc)
          oa[fc] = __builtin_amdgcn_mfma_f32_16x16x32_bf16(pf[ks], vf[fc][ks], oa[fc], 0, 0, 0);
        ol = __builtin_amdgcn_mfma_f32_16x16x32_bf16(pf[ks], v1, ol, 0, 0, 0);
      }
      __builtin_amdgcn_s_setprio(0);
    }
    cur ^= 1;
  }

  {
    float li[4];
    #pragma unroll
    for (int j=0;j<4;++j) li[j] = 1.f/__shfl(ol[j], l4<<4);
    #pragma unroll
    for (int fc=0; fc<4; ++fc){
      int col = h*64 + fc*16 + l15;
      size_t r0 = (size_t)(b*SEQ + qt*128 + w*16 + l4*4);
      ao[(r0+0)*D_MODEL + col] = f2b(oa[fc][0]*li[0]);
      ao[(r0+1)*D_MODEL + col] = f2b(oa[fc][1]*li[1]);
      ao[(r0+2)*D_MODEL + col] = f2b(oa[fc][2]*li[2]);
      ao[(r0+3)*D_MODEL + col] = f2b(oa[fc][3]*li[3]);
    }
  }
}

// ---------- final LN: out = LN(x2b + F0 + F1), all bf16 in, fp32 out ----------
__global__ __launch_bounds__(256) void lnfin_k(const unsigned int* __restrict__ X2b,
    const unsigned int* __restrict__ F0, const unsigned int* __restrict__ F1,
    const float* __restrict__ g, const float* __restrict__ be, float* __restrict__ outf){
  __shared__ float lds[16];
  const size_t off2 = (size_t)blockIdx.x * 256;
  const int tid = threadIdx.x;
  unsigned xv = X2b[off2+tid], f0 = F0[off2+tid], f1 = F1[off2+tid];
  float a0 = blo(xv) + blo(f0) + blo(f1);
  float a1 = bhi(xv) + bhi(f0) + bhi(f1);
  float s1 = a0+a1, s2 = a0*a0+a1*a1;
  block_sum2(s1, s2, lds);
  float mean = s1 * (1.f/512.f);
  float var  = s2 * (1.f/512.f) - mean*mean;
  float rstd = rsqrtf(var + 1e-5f);
  float2 gg = ((const float2*)g)[tid], bb = ((const float2*)be)[tid];
  float2 r;
  r.x = (a0-mean)*rstd*gg.x + bb.x;
  r.y = (a1-mean)*rstd*gg.y + bb.y;
  ((float2*)outf)[off2+tid] = r;
}

// ---------- fused: x1 = LN(shifted + P0 + P1); scan prep; all bf16 I/O ----------
__global__ __launch_bounds__(256) void ln_scan_k(const unsigned int* __restrict__ Ab,
    const unsigned int* __restrict__ P0, const unsigned int* __restrict__ P1,
    const float* __restrict__ g, const float* __restrict__ be, const float* __restrict__ tm,
    unsigned int* __restrict__ x1b, unsigned int* __restrict__ dec, unsigned int* __restrict__ u,
    float* __restrict__ dm, float* __restrict__ es){
  __shared__ float lds[16];
  const size_t row = blockIdx.x;
  const size_t off2 = row * 256;
  const int tid = threadIdx.x;
  unsigned av = Ab[off2+tid], pv = P0[off2+tid], qv = P1[off2+tid];
  float a0 = blo(av) + blo(pv) + blo(qv);
  float a1 = bhi(av) + bhi(pv) + bhi(qv);
  float s1 = a0+a1, s2 = a0*a0+a1*a1;
  block_sum2(s1, s2, lds);
  float mean = s1 * (1.f/512.f);
  float var  = s2 * (1.f/512.f) - mean*mean;
  float rstd = rsqrtf(var + 1e-5f);
  float2 gg = ((const float2*)g)[tid], bb = ((const float2*)be)[tid], tt = ((const float2*)tm)[tid];
  float r0 = (a0-mean)*rstd*gg.x + bb.x;
  float r1 = (a1-mean)*rstd*gg.y + bb.y;
  x1b[off2+tid] = bpack(r0, r1);
  float dc0 = sigmoidf_(r0*tt.x), dc1 = sigmoidf_(r1*tt.y);
  float e0 = expf(r0), e1 = expf(r1);
  dec[off2+tid] = bpack(dc0, dc1);
  u[off2+tid]   = bpack(e0*r0, e1*r1);
  float dsum = dc0+dc1, esum = e0+e1;
  block_sum2(dsum, esum, lds);
  if (tid==0){ dm[row]=dsum*(1.f/512.f); es[row]=esum; }
}

// ---------- fused: coupled = LN(sigmoid(R)*V); x2 = LN(X1+coupled); bf16 I/O ----------
__global__ __launch_bounds__(256) void ln2x_k(const unsigned int* __restrict__ R,
    const unsigned int* __restrict__ V, const unsigned int* __restrict__ X1,
    const float* __restrict__ g1, const float* __restrict__ b1_,
    const float* __restrict__ g2, const float* __restrict__ b2_,
    unsigned int* __restrict__ x2b){
  __shared__ float lds[16];
  const size_t off2 = (size_t)blockIdx.x * 256;
  const int tid = threadIdx.x;
  unsigned rv = R[off2+tid], vv = V[off2+tid];
  float a0 = sigmoidf_(blo(rv))*blo(vv);
  float a1 = sigmoidf_(bhi(rv))*bhi(vv);
  float s1 = a0+a1, s2 = a0*a0+a1*a1;
  block_sum2(s1, s2, lds);
  float mean = s1*(1.f/512.f);
  float var  = s2*(1.f/512.f) - mean*mean;
  float rstd = rsqrtf(var + 1e-5f);
  float2 g1v = ((const float2*)g1)[tid], b1v = ((const float2*)b1_)[tid];
  float c0 = (a0-mean)*rstd*g1v.x + b1v.x;
  float c1 = (a1-mean)*rstd*g1v.y + b1v.y;
  unsigned x1v = X1[off2+tid];
  float t0 = blo(x1v) + c0, t1 = bhi(x1v) + c1;
  float u1 = t0+t1, u2 = t0*t0+t1*t1;
  block_sum2(u1, u2, lds);
  float mean2 = u1*(1.f/512.f);
  float var2  = u2*(1.f/512.f) - mean2*mean2;
  float rstd2 = rsqrtf(var2 + 1e-5f);
  float2 g2v = ((const float2*)g2)[tid], b2v = ((const float2*)b2_)[tid];
  float r0 = (t0-mean2)*rstd2*g2v.x + b2v.x;
  float r1 = (t1-mean2)*rstd2*g2v.y + b2v.y;
  x2b[off2+tid] = bpack(r0, r1);
}

// ---------- b scan phase 1 (bf16 in, 256 threads, paired) ----------
__global__ __launch_bounds__(256) void bscan_p1(const unsigned int* __restrict__ decay,
    const unsigned int* __restrict__ u, float* __restrict__ Gc, float* __restrict__ Uc){
  const int c = blockIdx.x, b = blockIdx.y, t = threadIdx.x;
  size_t base2 = ((size_t)b*SEQ + (size_t)c*CHUNK)*256 + t;
  float G0=1.f, G1=1.f, U0=0.f, U1=0.f;
  for (int i=0;i<CHUNK;++i){
    unsigned dv = decay[base2 + (size_t)i*256];
    unsigned uv = u[base2 + (size_t)i*256];
    float g0 = blo(dv), g1 = bhi(dv);
    U0 = g0*U0 + blo(uv); G0 *= g0;
    U1 = g1*U1 + bhi(uv); G1 *= g1;
  }
  size_t idx2 = ((size_t)b*NCHUNK + c)*256 + t;
  float2 gv; gv.x=G0; gv.y=G1;
  float2 uv2; uv2.x=U0; uv2.y=U1;
  ((float2*)Gc)[idx2] = gv;
  ((float2*)Uc)[idx2] = uv2;
}

// ---------- merged: b-scan phase 2 (blocks 0-3, batched prefetch) + 'a' scan ----------
__global__ __launch_bounds__(512) void scan2_k(const float* __restrict__ Gc, const float* __restrict__ Uc,
    float* __restrict__ binit, const float* __restrict__ dm, const float* __restrict__ es,
    float* __restrict__ a_out){
  __shared__ float sG[512], sU[512];
  if (blockIdx.x < 4){
    const int b = blockIdx.x, d = threadIdx.x;
    float cur = 0.f;
    for (int c0=0; c0<NCHUNK; c0+=8){
      float g[8], u[8];
      #pragma unroll
      for (int i=0;i<8;++i){
        size_t idx = ((size_t)b*NCHUNK + c0+i)*D_MODEL + d;
        g[i] = Gc[idx]; u[i] = Uc[idx];
      }
      #pragma unroll
      for (int i=0;i<8;++i){
        size_t idx = ((size_t)b*NCHUNK + c0+i)*D_MODEL + d;
        binit[idx] = cur;
        cur = g[i]*cur + u[i];
      }
    }
  } else {
    const int b = blockIdx.x - 4, tid = threadIdx.x;
    const float* dmb = dm + (size_t)b*SEQ;
    const float* esb = es + (size_t)b*SEQ;
    const int t0 = tid*4;
    float gi[4], ui[4];
    #pragma unroll
    for (int i=0;i<4;++i){ gi[i]=dmb[t0+i]; ui[i]=esb[t0+i]; }
    float G=1.f, U=0.f;
    #pragma unroll
    for (int i=0;i<4;++i){ U = gi[i]*U + ui[i]; G *= gi[i]; }
    sG[tid]=G; sU[tid]=U;
    __syncthreads();
    for (int off=1; off<512; off<<=1){
      float pg=1.f, pu=0.f;
      bool act = tid >= off;
      if (act){ pg = sG[tid-off]; pu = sU[tid-off]; }
      __syncthreads();
      if (act){ sU[tid] = sG[tid]*pu + sU[tid]; sG[tid] = sG[tid]*pg; }
      __syncthreads();
    }
    float a = (tid==0) ? 0.f : sU[tid-1];
    #pragma unroll
    for (int i=0;i<4;++i){ a = gi[i]*a + ui[i]; a_out[(size_t)b*SEQ + t0 + i] = a; }
  }
}

// ---------- fused p3 + LN(merged), bf16 I/O, 256 threads paired ----------
__global__ __launch_bounds__(256) void p3ln_k(const unsigned int* __restrict__ decay,
    const unsigned int* __restrict__ u,
    const float* __restrict__ binit, const float* __restrict__ a,
    const float* __restrict__ g, const float* __restrict__ be,
    unsigned int* __restrict__ mb){
  __shared__ float lds[16];
  const int c = blockIdx.x, b = blockIdx.y, t = threadIdx.x;
  size_t base2 = ((size_t)b*SEQ + (size_t)c*CHUNK)*256 + t;
  float2 bv = ((const float2*)binit)[((size_t)b*NCHUNK + c)*256 + t];
  float2 gg = ((const float2*)g)[t], bb = ((const float2*)be)[t];
  for (int i=0;i<CHUNK;++i){
    unsigned dv = decay[base2 + (size_t)i*256];
    unsigned uv = u[base2 + (size_t)i*256];
    bv.x = blo(dv)*bv.x + blo(uv);
    bv.y = bhi(dv)*bv.y + bhi(uv);
    float av = a[(size_t)b*SEQ + (size_t)c*CHUNK + i];
    float inv = 1.f/(av + 1e-8f);
    float v0 = bv.x*inv, v1 = bv.y*inv;
    float s1 = v0+v1, s2 = v0*v0+v1*v1;
    block_sum2(s1, s2, lds);
    float mean = s1*(1.f/512.f);
    float var  = s2*(1.f/512.f) - mean*mean;
    float rstd = rsqrtf(var + 1e-5f);
    mb[base2 + (size_t)i*256] = bpack((v0-mean)*rstd*gg.x + bb.x,
                                      (v1-mean)*rstd*gg.y + bb.y);
  }
}

extern "C" void kernel_launch(void* const* d_in, const int* in_sizes, int n_in,
                              void* d_out, int out_size, void* d_ws, size_t ws_size,
                              hipStream_t stream){
  const float* x     = (const float*)d_in[0];
  const float* xp    = (const float*)d_in[1];
  const float* mu    = (const float*)d_in[2];
  const float* in_w  = (const float*)d_in[3];
  const float* in_b  = (const float*)d_in[4];
  const float* out_w = (const float*)d_in[5];
  const float* out_b = (const float*)d_in[6];
  const float* ln1_g = (const float*)d_in[7];
  const float* ln1_b = (const float*)d_in[8];
  const float* tm    = (const float*)d_in[9];
  const float* sm_g  = (const float*)d_in[10];
  const float* sm_b  = (const float*)d_in[11];
  const float* wr_w  = (const float*)d_in[12];
  const float* wr_b  = (const float*)d_in[13];
  const float* wv_w  = (const float*)d_in[14];
  const float* wv_b  = (const float*)d_in[15];
  const float* sc_g  = (const float*)d_in[16];
  const float* sc_b  = (const float*)d_in[17];
  const float* ln2_g = (const float*)d_in[18];
  const float* ln2_b = (const float*)d_in[19];
  const float* w1    = (const float*)d_in[20];
  const float* b1    = (const float*)d_in[21];
  const float* w2    = (const float*)d_in[22];
  const float* b2    = (const float*)d_in[23];
  const float* ln3_g = (const float*)d_in[24];
  const float* ln3_b = (const float*)d_in[25];
  float* out = (float*)d_out;
  float* ws  = (float*)d_ws;

  const size_t N = (size_t)M_TOK*D_MODEL;   // 4,194,304
  unsigned short* P0b = (unsigned short*)ws;            // proj half0 bf16 (8MB)
  unsigned short* X1b = (unsigned short*)ws + N;        // x1 bf16 (8MB)
  unsigned short* F0  = (unsigned short*)(ws + N);      // ffn2 half0 (8MB)
  unsigned short* F1  = (unsigned short*)(ws + N) + N;  // ffn2 half1 (8MB)
  unsigned short* P1b = (unsigned short*)(ws + 2*N);    // proj half1 bf16 (8MB)
  float* EX  = ws + 3*N;
  float* dm    = EX;
  float* es    = EX + 8192;
  float* aarr  = EX + 16384;
  float* Gc    = EX + 24576;
  float* Uc    = Gc + 131072;
  float* binit = Uc + 131072;

  unsigned short* SB = (unsigned short*)(ws + 3*N + N/4);
  unsigned short* Wq = SB;
  unsigned short* Wo = Wq + 786432;
  unsigned short* Wr = Wo + 262144;
  unsigned short* Wv = Wr + 262144;
  unsigned short* W1 = Wv + 262144;
  unsigned short* W2 = W1 + 1048576;
  unsigned short* Xb = W2 + 1048576;       // shifted bf16, later x2 bf16
  unsigned short* Mb = Xb + N;             // merged bf16
  unsigned short* U  = Mb + N;
  unsigned short* Qb  = U;                 // qkv bf16 (24MB)
  unsigned short* AOb = U + 12*1024*1024;  // attn out bf16 (8MB)
  unsigned short* ub   = U;                // after Qb dead
  unsigned short* decb = U + 12*1024*1024; // after AOb dead
  unsigned short* Rb   = U;                // after ub dead
  unsigned short* Vb   = U + 4*1024*1024;
  unsigned short* Hb   = U;                // FFN hidden (32MB)

  // 0. weight converts + shift (bf16 only)
  cvtshift_k<<<7680, 256, 0, stream>>>(in_w, out_w, wr_w, wv_w, w1, w2,
                                       Wq, Wo, Wr, Wv, W1, W2,
                                       x, xp, mu, Xb);
  // 1. qkv -> Qb
  mgemm_k<0,1><<<dim3(12,64), 256, 0, stream>>>(Xb, Wq, in_b, nullptr, Qb, 1536, 512);
  // 2. flash attention -> AOb (QBLK=128, grid 512, 8 waves — R11 config)
  fattn_k<<<dim3(SEQ/128, NH, BATCH), 512, 0, stream>>>(Qb, AOb);
  // 3. out-proj split-K -> P0b (bias) + P1b
  mgemm64_k<0,0,1><<<dim3(16,64), 256, 0, stream>>>(AOb, Wo, nullptr, out_b, nullptr,
                                                    P0b, P1b, 512, 512);
  // 4. x1 = LN(shifted + P0 + P1) -> X1b; decb/ub; dm/es
  ln_scan_k<<<M_TOK, 256, 0, stream>>>((const unsigned int*)Xb, (const unsigned int*)P0b,
                                       (const unsigned int*)P1b,
                                       ln1_g, ln1_b, tm,
                                       (unsigned int*)X1b, (unsigned int*)decb, (unsigned int*)ub,
                                       dm, es);
  // 5. b-scan phase 1
  bscan_p1<<<dim3(NCHUNK, BATCH), 256, 0, stream>>>((const unsigned int*)decb, (const unsigned int*)ub, Gc, Uc);
  // 6. merged p2 (batched prefetch) + ascan
  scan2_k<<<8, 512, 0, stream>>>(Gc, Uc, binit, dm, es, aarr);
  // 7. p3 + LN(merged) -> Mb
  p3ln_k<<<dim3(NCHUNK, BATCH), 256, 0, stream>>>((const unsigned int*)decb, (const unsigned int*)ub,
                                                  binit, aarr, sm_g, sm_b, (unsigned int*)Mb);
  // 8. r -> Rb, v -> Vb (bf16, fused)
  mgemm64_k<0,1,0><<<dim3(16,64), 256, 0, stream>>>(Mb, Wr, Wv, wr_b, wv_b,
                                                    Rb, Vb, 512, 512);
  // 9. coupled-LN + x2-LN -> Xb (x2 bf16)
  ln2x_k<<<M_TOK, 256, 0, stream>>>((const unsigned int*)Rb, (const unsigned int*)Vb,
                                    (const unsigned int*)X1b,
                                    sc_g, sc_b, ln2_g, ln2_b, (unsigned int*)Xb);
  // 10. hidden = relu(x2 @ w1.T + b1) -> Hb
  mgemm_k<1,1><<<dim3(16,64), 256, 0, stream>>>(Xb, W1, b1, nullptr, Hb, 2048, 512);
  // 11. ffnout split-K -> F0 (bias) + F1
  mgemm64_k<0,0,1><<<dim3(16,64), 256, 0, stream>>>(Hb, W2, nullptr, b2, nullptr,
                                                    F0, F1, 512, 2048);
  // 12. out = LN(x2 + F0 + F1)
  lnfin_k<<<M_TOK, 256, 0, stream>>>((const unsigned int*)Xb, (const unsigned int*)F0,
                                     (const unsigned int*)F1, ln3_g, ln3_b, out);
}

// Round 14
// 237.909 us; speedup vs baseline: 1.1042x; 1.0552x over previous
//
#include <hip/hip_runtime.h>
#include <math.h>

#define D_MODEL 512
#define SEQ     2048
#define BATCH   4
#define NH      8
#define HD      64
#define CHUNK   32
#define NCHUNK  64
#define M_TOK   (BATCH*SEQ)   // 8192

typedef __attribute__((ext_vector_type(8))) short bhalf8;   // 8 bf16 = 4 VGPR
typedef __attribute__((ext_vector_type(4))) float f32x4;

__device__ __forceinline__ float sigmoidf_(float x){ return 1.f/(1.f+expf(-x)); }

__device__ __forceinline__ unsigned short f2b(float f){   // fp32 -> bf16 RNE
  unsigned u = __float_as_uint(f);
  u += 0x7FFFu + ((u>>16)&1u);
  return (unsigned short)(u>>16);
}
__device__ __forceinline__ float b2f(unsigned short h){
  return __uint_as_float(((unsigned)h)<<16);
}
__device__ __forceinline__ float blo(unsigned v){ return __uint_as_float(v<<16); }
__device__ __forceinline__ float bhi(unsigned v){ return __uint_as_float(v & 0xFFFF0000u); }
__device__ __forceinline__ unsigned bpack(float a, float b){
  return (unsigned)f2b(a) | ((unsigned)f2b(b)<<16);
}

__device__ __forceinline__ void gll16(const void* g, void* l){
  __builtin_amdgcn_global_load_lds(
      (const __attribute__((address_space(1))) unsigned int*)g,
      (__attribute__((address_space(3))) unsigned int*)l, 16, 0, 0);
}

__device__ __forceinline__ float exp2_hw(float x){
  float r;
  asm volatile("v_exp_f32 %0, %1" : "=v"(r) : "v"(x));
  return r;
}

// ---------- wave-level paired reduction (64 lanes, no barriers/LDS) ----------
__device__ __forceinline__ void wave_red2(float& a, float& b){
  #pragma unroll
  for (int o=32;o>0;o>>=1){ a += __shfl_xor(a,o); b += __shfl_xor(b,o); }
}

// ---------- merged: weight converts + shift (bf16 out only) ----------
__global__ void cvtshift_k(const float* __restrict__ s0,const float* __restrict__ s1,
                           const float* __restrict__ s2,const float* __restrict__ s3,
                           const float* __restrict__ s4,const float* __restrict__ s5,
                           unsigned short* __restrict__ d0,unsigned short* __restrict__ d1,
                           unsigned short* __restrict__ d2,unsigned short* __restrict__ d3,
                           unsigned short* __restrict__ d4,unsigned short* __restrict__ d5,
                           const float* __restrict__ x, const float* __restrict__ xp,
                           const float* __restrict__ mu,
                           unsigned short* __restrict__ ob){
  int t = blockIdx.x*blockDim.x + threadIdx.x;
  if (t < 917504){
    int j = t;
    const float* s; unsigned short* d;
    if (j < 196608){ s=s0; d=d0; }
    else if ((j-=196608) < 65536){ s=s1; d=d1; }
    else if ((j-=65536)  < 65536){ s=s2; d=d2; }
    else if ((j-=65536)  < 65536){ s=s3; d=d3; }
    else if ((j-=65536)  < 262144){ s=s4; d=d4; }
    else { j-=262144; s=s5; d=d5; }
    float4 v = ((const float4*)s)[j];
    uint2 p; p.x = bpack(v.x, v.y); p.y = bpack(v.z, v.w);
    ((uint2*)d)[j] = p;
  } else {
    int i = t - 917504;   // 0 .. 1048575
    float m = mu[0];
    float4 a = ((const float4*)x)[i], p = ((const float4*)xp)[i];
    float4 r;
    r.x = m*a.x + (1.f-m)*p.x; r.y = m*a.y + (1.f-m)*p.y;
    r.z = m*a.z + (1.f-m)*p.z; r.w = m*a.w + (1.f-m)*p.w;
    uint2 q; q.x = bpack(r.x, r.y); q.y = bpack(r.z, r.w);
    ((uint2*)ob)[i] = q;
  }
}

// ---------- bf16 MFMA GEMM 128x128, XCD-swizzled ----------
template<int ACT, int OUTB>
__global__ __launch_bounds__(256) void mgemm_k(const unsigned short* __restrict__ A,
    const unsigned short* __restrict__ W, const float* __restrict__ bias,
    float* __restrict__ Yf, unsigned short* __restrict__ Yb, int Nd, int K){
  __shared__ unsigned short As[128*64];
  __shared__ unsigned short Bs[128*64];
  const int tid = threadIdx.x;
  const int w = tid>>6, lane = tid&63;
  const int l15 = lane&15, l4 = lane>>4;
  const int wr = w>>1, wc = w&1;
  const int nwg = gridDim.x*gridDim.y;
  const int orig = blockIdx.y*gridDim.x + blockIdx.x;
  const int swz = (orig&7)*(nwg>>3) + (orig>>3);
  const int bn = swz % gridDim.x;
  const int bm = swz / gridDim.x;

  const size_t Kb = (size_t)K*2;
  const int srow  = lane>>3;
  const int sbyte = ((lane&7)*16) ^ (srow<<4);
  const char* Ag = (const char*)A + (size_t)(bm*128)*Kb + sbyte;
  const char* Wg = (const char*)W + (size_t)(bn*128)*Kb + sbyte;

  f32x4 acc[4][4];
  const f32x4 z = {0.f,0.f,0.f,0.f};
  #pragma unroll
  for (int i=0;i<4;++i)
    #pragma unroll
    for (int j=0;j<4;++j) acc[i][j] = z;

  const int KT = K/64;
  for (int kt=0; kt<KT; ++kt){
    if (kt) __syncthreads();
    const size_t kOff = (size_t)kt*128;
    #pragma unroll
    for (int i=0;i<4;++i){
      int c = w*4 + i;
      int r = c*8 + srow;
      gll16(Ag + (size_t)r*Kb + kOff, (char*)As + c*1024);
      gll16(Wg + (size_t)r*Kb + kOff, (char*)Bs + c*1024);
    }
    __syncthreads();

    bhalf8 af[4][2], bf_[4][2];
    #pragma unroll
    for (int fr=0; fr<4; ++fr){
      int row = wr*64 + fr*16 + l15;
      #pragma unroll
      for (int ks=0; ks<2; ++ks){
        int byo = (l4*16 + ks*64) ^ ((row&7)<<4);
        af[fr][ks] = *(const bhalf8*)((const char*)As + row*128 + byo);
      }
    }
    #pragma unroll
    for (int fc=0; fc<4; ++fc){
      int row = wc*64 + fc*16 + l15;
      #pragma unroll
      for (int ks=0; ks<2; ++ks){
        int byo = (l4*16 + ks*64) ^ ((row&7)<<4);
        bf_[fc][ks] = *(const bhalf8*)((const char*)Bs + row*128 + byo);
      }
    }
    #pragma unroll
    for (int ks=0; ks<2; ++ks)
      #pragma unroll
      for (int fr=0; fr<4; ++fr)
        #pragma unroll
        for (int fc=0; fc<4; ++fc)
          acc[fr][fc] = __builtin_amdgcn_mfma_f32_16x16x32_bf16(af[fr][ks], bf_[fc][ks], acc[fr][fc], 0, 0, 0);
  }

  const int rowBase = bm*128 + wr*64;
  const int colBase = bn*128 + wc*64;
  #pragma unroll
  for (int fc=0; fc<4; ++fc){
    int col = colBase + fc*16 + l15;
    float bv = bias[col];
    #pragma unroll
    for (int fr=0; fr<4; ++fr){
      #pragma unroll
      for (int j=0; j<4; ++j){
        int row = rowBase + fr*16 + l4*4 + j;
        float v = acc[fr][fc][j] + bv;
        if (ACT) v = fmaxf(v, 0.f);
        if (OUTB) Yb[(size_t)row*Nd + col] = f2b(v);
        else      Yf[(size_t)row*Nd + col] = v;
      }
    }
  }
}

// ---------- bf16 MFMA GEMM 128x64, XCD-swizzled; FUSE2 or SPLITK ----------
template<int ACT, int FUSE2, int SPLITK>
__global__ __launch_bounds__(256) void mgemm64_k(const unsigned short* __restrict__ A,
    const unsigned short* __restrict__ W0, const unsigned short* __restrict__ W1v,
    const float* __restrict__ bias0, const float* __restrict__ bias1,
    unsigned short* __restrict__ Yb0, unsigned short* __restrict__ Yb1,
    int Nd, int K){
  __shared__ unsigned short As[128*64];
  __shared__ unsigned short Bs[64*64];
  const int tid = threadIdx.x;
  const int w = tid>>6, lane = tid&63;
  const int l15 = lane&15, l4 = lane>>4;
  const int wr = w>>1, wc = w&1;
  const int nwg = gridDim.x*gridDim.y;
  const int orig = blockIdx.y*gridDim.x + blockIdx.x;
  const int swz = (orig&7)*(nwg>>3) + (orig>>3);
  int bn = swz % gridDim.x;
  const int bm = swz / gridDim.x;
  const unsigned short* W = W0;
  const float* bias = bias0;
  unsigned short* Yb = Yb0;
  int half = 0;
  if (FUSE2 && bn >= 8){ W = W1v; bias = bias1; Yb = Yb1; bn -= 8; }
  if (SPLITK && bn >= 8){ half = 1; Yb = Yb1; bn -= 8; }

  const int Ksr = SPLITK ? (K>>1) : K;
  const size_t Kb = (size_t)K*2;
  const size_t hOff = (size_t)half * Ksr * 2;
  const int srow  = lane>>3;
  const int sbyte = ((lane&7)*16) ^ (srow<<4);
  const char* Ag = (const char*)A + (size_t)(bm*128)*Kb + hOff + sbyte;
  const char* Wg = (const char*)W + (size_t)(bn*64)*Kb + hOff + sbyte;

  f32x4 acc[4][2];
  const f32x4 z = {0.f,0.f,0.f,0.f};
  #pragma unroll
  for (int i=0;i<4;++i)
    #pragma unroll
    for (int j=0;j<2;++j) acc[i][j] = z;

  const int KT = Ksr/64;
  for (int kt=0; kt<KT; ++kt){
    if (kt) __syncthreads();
    const size_t kOff = (size_t)kt*128;
    #pragma unroll
    for (int i=0;i<4;++i){
      int c = w*4 + i;
      int r = c*8 + srow;
      gll16(Ag + (size_t)r*Kb + kOff, (char*)As + c*1024);
    }
    #pragma unroll
    for (int i=0;i<2;++i){
      int c = w*2 + i;
      int r = c*8 + srow;
      gll16(Wg + (size_t)r*Kb + kOff, (char*)Bs + c*1024);
    }
    __syncthreads();

    bhalf8 af[4][2], bf_[2][2];
    #pragma unroll
    for (int fr=0; fr<4; ++fr){
      int row = wr*64 + fr*16 + l15;
      #pragma unroll
      for (int ks=0; ks<2; ++ks){
        int byo = (l4*16 + ks*64) ^ ((row&7)<<4);
        af[fr][ks] = *(const bhalf8*)((const char*)As + row*128 + byo);
      }
    }
    #pragma unroll
    for (int fc=0; fc<2; ++fc){
      int row = wc*32 + fc*16 + l15;
      #pragma unroll
      for (int ks=0; ks<2; ++ks){
        int byo = (l4*16 + ks*64) ^ ((row&7)<<4);
        bf_[fc][ks] = *(const bhalf8*)((const char*)Bs + row*128 + byo);
      }
    }
    #pragma unroll
    for (int ks=0; ks<2; ++ks)
      #pragma unroll
      for (int fr=0; fr<4; ++fr)
        #pragma unroll
        for (int fc=0; fc<2; ++fc)
          acc[fr][fc] = __builtin_amdgcn_mfma_f32_16x16x32_bf16(af[fr][ks], bf_[fc][ks], acc[fr][fc], 0, 0, 0);
  }

  const int rowBase = bm*128 + wr*64;
  const int colBase = bn*64 + wc*32;
  #pragma unroll
  for (int fc=0; fc<2; ++fc){
    int col = colBase + fc*16 + l15;
    float bv = (SPLITK && half) ? 0.f : bias[col];
    #pragma unroll
    for (int fr=0; fr<4; ++fr){
      #pragma unroll
      for (int j=0; j<4; ++j){
        int row = rowBase + fr*16 + l4*4 + j;
        float v = acc[fr][fc][j] + bv;
        if (ACT) v = fmaxf(v, 0.f);
        Yb[(size_t)row*Nd + col] = f2b(v);
      }
    }
  }
}

// ---------- bf16 MFMA flash attention (R11/R13 version — known-good 71us) ----------
__global__ __launch_bounds__(512, 4) void fattn_k(const unsigned short* __restrict__ qkv,
                                                  unsigned short* __restrict__ ao){
  __shared__ unsigned short Ks[2][64*64];
  __shared__ unsigned short Vt[2][64*64];
  __shared__ unsigned short Ps[128*64];
  const int nwg = gridDim.x*gridDim.y*gridDim.z;   // 512
  const int orig = (blockIdx.z*gridDim.y + blockIdx.y)*gridDim.x + blockIdx.x;
  const int swz = (orig&7)*(nwg>>3) + (orig>>3);
  const int qt = swz % gridDim.x;
  const int rem = swz / gridDim.x;
  const int h = rem % gridDim.y;
  const int b = rem / gridDim.y;
  const int tid = threadIdx.x, w = tid>>6, lane = tid&63;
  const int l15 = lane&15, l4 = lane>>4;
  const size_t rowB = 3072;
  const char* base = (const char*)qkv + (size_t)b*SEQ*rowB;
  const char* Kg = base + 1024 + h*128;
  const char* Vg = base + 2048 + h*128;
  const float C2 = 0.18033688f;             // 0.125 * log2(e)

  bhalf8 qf[2];
  {
    const char* qrow = base + (size_t)(qt*128 + w*16 + l15)*rowB + h*128;
    qf[0] = *(const bhalf8*)(qrow + l4*16);
    qf[1] = *(const bhalf8*)(qrow + l4*16 + 64);
  }
  bhalf8 v1;
  {
    short o = (l15==0) ? (short)0x3F80 : (short)0;
    v1 = (bhalf8){o,o,o,o,o,o,o,o};
  }

  const f32x4 z = {0.f,0.f,0.f,0.f};
  f32x4 oa[4], ol = z;
  #pragma unroll
  for (int i=0;i<4;++i) oa[i] = z;
  float mj = -INFINITY;

  const int srow  = lane>>3;
  const int sbyte = ((lane&7)*16) ^ (srow<<4);
  const int vd = lane;
  const int vsel = (vd>>3)&1;

  unsigned short vload[8];
  {
    int r = w*8 + srow;
    gll16(Kg + (size_t)r*rowB + sbyte, (char*)Ks[0] + w*1024);
  }
  #pragma unroll
  for (int i=0;i<8;++i)
    vload[i] = *(const unsigned short*)(Vg + (size_t)(w*8 + i)*rowB + vd*2);

  int cur = 0;
  for (int kt=0; kt<SEQ/64; ++kt){
    #pragma unroll
    for (int i=0;i<2;++i){
      int p = i ^ vsel;
      unsigned lo = (unsigned)vload[p*4+0] | ((unsigned)vload[p*4+1]<<16);
      unsigned hi = (unsigned)vload[p*4+2] | ((unsigned)vload[p*4+3]<<16);
      uint2 pk; pk.x = lo; pk.y = hi;
      int byo = (w*16 + p*8) ^ ((vd&7)<<4);
      *(uint2*)((char*)Vt[cur] + vd*128 + byo) = pk;
    }
    __syncthreads();

    if (kt+1 < SEQ/64){
      int r = w*8 + srow;
      gll16(Kg + (size_t)((kt+1)*64 + r)*rowB + sbyte, (char*)Ks[cur^1] + w*1024);
      #pragma unroll
      for (int i=0;i<8;++i)
        vload[i] = *(const unsigned short*)(Vg + (size_t)((kt+1)*64 + w*8 + i)*rowB + vd*2);
    }

    bhalf8 kf[4][2];
    #pragma unroll
    for (int fc=0; fc<4; ++fc){
      int kr = fc*16 + l15;
      #pragma unroll
      for (int ks=0; ks<2; ++ks){
        int byo = (l4*16 + ks*64) ^ ((kr&7)<<4);
        kf[fc][ks] = *(const bhalf8*)((const char*)Ks[cur] + kr*128 + byo);
      }
    }
    f32x4 s[4];
    #pragma unroll
    for (int i=0;i<4;++i) s[i] = z;
    __builtin_amdgcn_s_setprio(1);
    #pragma unroll
    for (int ks=0; ks<2; ++ks)
      #pragma unroll
      for (int fc=0; fc<4; ++fc)
        s[fc] = __builtin_amdgcn_mfma_f32_16x16x32_bf16(kf[fc][ks], qf[ks], s[fc], 0, 0, 0);
    __builtin_amdgcn_s_setprio(0);

    {
      float rm0 = fmaxf(fmaxf(s[0][0],s[0][1]), fmaxf(s[0][2],s[0][3]));
      float rm1 = fmaxf(fmaxf(s[1][0],s[1][1]), fmaxf(s[1][2],s[1][3]));
      float rm2 = fmaxf(fmaxf(s[2][0],s[2][1]), fmaxf(s[2][2],s[2][3]));
      float rm3 = fmaxf(fmaxf(s[3][0],s[3][1]), fmaxf(s[3][2],s[3][3]));
      float rm = fmaxf(fmaxf(rm0,rm1), fmaxf(rm2,rm3));
      rm = fmaxf(rm, __shfl_xor(rm,16));
      rm = fmaxf(rm, __shfl_xor(rm,32));
      float tmax = rm * C2;
      if (__any(tmax > mj + 8.f)){
        float mn = fmaxf(mj, tmax);
        float sc = exp2_hw(mj - mn);
        mj = mn;
        float scj0 = __shfl(sc, l4*4+0), scj1 = __shfl(sc, l4*4+1);
        float scj2 = __shfl(sc, l4*4+2), scj3 = __shfl(sc, l4*4+3);
        #pragma unroll
        for (int fc=0; fc<4; ++fc){
          oa[fc][0] *= scj0; oa[fc][1] *= scj1;
          oa[fc][2] *= scj2; oa[fc][3] *= scj3;
        }
        ol[0] *= scj0; ol[1] *= scj1; ol[2] *= scj2; ol[3] *= scj3;
      }
      int qrow = w*16 + l15;
      #pragma unroll
      for (int fc=0; fc<4; ++fc){
        float p0 = exp2_hw(fmaf(C2, s[fc][0], -mj));
        float p1 = exp2_hw(fmaf(C2, s[fc][1], -mj));
        float p2 = exp2_hw(fmaf(C2, s[fc][2], -mj));
        float p3 = exp2_hw(fmaf(C2, s[fc][3], -mj));
        unsigned lo, hi;
        asm volatile("v_cvt_pk_bf16_f32 %0, %1, %2" : "=v"(lo) : "v"(p0), "v"(p1));
        asm volatile("v_cvt_pk_bf16_f32 %0, %1, %2" : "=v"(hi) : "v"(p2), "v"(p3));
        uint2 pk; pk.x = lo; pk.y = hi;
        int byo = (fc*32 + l4*8) ^ ((l15&7)<<4);
        *(uint2*)((char*)Ps + qrow*128 + byo) = pk;
      }
    }

    bhalf8 vf[4][2];
    #pragma unroll
    for (int fc=0; fc<4; ++fc){
      int d = fc*16 + l15;
      #pragma unroll
      for (int ks=0; ks<2; ++ks){
        int byo = (ks*64 + l4*16) ^ ((d&7)<<4);
        vf[fc][ks] = *(const bhalf8*)((const char*)Vt[cur] + d*128 + byo);
      }
    }
    {
      int qrow = w*16 + l15;
      bhalf8 pf[2];
      #pragma unroll
      for (int ks=0; ks<2; ++ks){
        int byo = (ks*64 + l4*16) ^ ((l15&7)<<4);
        pf[ks] = *(const bhalf8*)((const char*)Ps + qrow*128 + byo);
      }
      __builtin_amdgcn_s_setprio(1);
      #pragma unroll
      for (int ks=0; ks<2; ++ks){
        #pragma unroll
        for (int fc=0; fc<4; ++fc)
          oa[fc] = __builtin_amdgcn_mfma_f32_16x16x32_bf16(pf[ks], vf[fc][ks], oa[fc], 0, 0, 0);
        ol = __builtin_amdgcn_mfma_f32_16x16x32_bf16(pf[ks], v1, ol, 0, 0, 0);
      }
      __builtin_amdgcn_s_setprio(0);
    }
    cur ^= 1;
  }

  {
    float li[4];
    #pragma unroll
    for (int j=0;j<4;++j) li[j] = 1.f/__shfl(ol[j], l4<<4);
    #pragma unroll
    for (int fc=0; fc<4; ++fc){
      int col = h*64 + fc*16 + l15;
      size_t r0 = (size_t)(b*SEQ + qt*128 + w*16 + l4*4);
      ao[(r0+0)*D_MODEL + col] = f2b(oa[fc][0]*li[0]);
      ao[(r0+1)*D_MODEL + col] = f2b(oa[fc][1]*li[1]);
      ao[(r0+2)*D_MODEL + col] = f2b(oa[fc][2]*li[2]);
      ao[(r0+3)*D_MODEL + col] = f2b(oa[fc][3]*li[3]);
    }
  }
}

// ---------- final LN (wave-per-row): out = LN(x2b + F0 + F1), fp32 out ----------
__global__ __launch_bounds__(256) void lnfin_k(const uint4* __restrict__ X2b,
    const uint4* __restrict__ F0, const uint4* __restrict__ F1,
    const float* __restrict__ g, const float* __restrict__ be, float* __restrict__ outf){
  const int row = blockIdx.x*4 + (threadIdx.x>>6);
  const int l = threadIdx.x & 63;
  const size_t i4 = (size_t)row*64 + l;
  uint4 xv = X2b[i4], f0 = F0[i4], f1 = F1[i4];
  float a[8];
  a[0]=blo(xv.x)+blo(f0.x)+blo(f1.x); a[1]=bhi(xv.x)+bhi(f0.x)+bhi(f1.x);
  a[2]=blo(xv.y)+blo(f0.y)+blo(f1.y); a[3]=bhi(xv.y)+bhi(f0.y)+bhi(f1.y);
  a[4]=blo(xv.z)+blo(f0.z)+blo(f1.z); a[5]=bhi(xv.z)+bhi(f0.z)+bhi(f1.z);
  a[6]=blo(xv.w)+blo(f0.w)+blo(f1.w); a[7]=bhi(xv.w)+bhi(f0.w)+bhi(f1.w);
  float s1=0.f, s2=0.f;
  #pragma unroll
  for (int k=0;k<8;++k){ s1 += a[k]; s2 += a[k]*a[k]; }
  wave_red2(s1, s2);
  float mean = s1 * (1.f/512.f);
  float var  = s2 * (1.f/512.f) - mean*mean;
  float rstd = rsqrtf(var + 1e-5f);
  float4 g0 = ((const float4*)g)[l*2], g1 = ((const float4*)g)[l*2+1];
  float4 b0 = ((const float4*)be)[l*2], b1 = ((const float4*)be)[l*2+1];
  float4 r0, r1;
  r0.x=(a[0]-mean)*rstd*g0.x+b0.x; r0.y=(a[1]-mean)*rstd*g0.y+b0.y;
  r0.z=(a[2]-mean)*rstd*g0.z+b0.z; r0.w=(a[3]-mean)*rstd*g0.w+b0.w;
  r1.x=(a[4]-mean)*rstd*g1.x+b1.x; r1.y=(a[5]-mean)*rstd*g1.y+b1.y;
  r1.z=(a[6]-mean)*rstd*g1.z+b1.z; r1.w=(a[7]-mean)*rstd*g1.w+b1.w;
  ((float4*)outf)[(size_t)row*128 + l*2]     = r0;
  ((float4*)outf)[(size_t)row*128 + l*2 + 1] = r1;
}

// ---------- ln_scan (wave-per-row): x1=LN(shift+P0+P1); scan prep ----------
__global__ __launch_bounds__(256) void ln_scan_k(const uint4* __restrict__ Ab,
    const uint4* __restrict__ P0, const uint4* __restrict__ P1,
    const float* __restrict__ g, const float* __restrict__ be, const float* __restrict__ tm,
    uint4* __restrict__ x1b, uint4* __restrict__ dec, uint4* __restrict__ u,
    float* __restrict__ dm, float* __restrict__ es){
  const int row = blockIdx.x*4 + (threadIdx.x>>6);
  const int l = threadIdx.x & 63;
  const size_t i4 = (size_t)row*64 + l;
  uint4 av = Ab[i4], pv = P0[i4], qv = P1[i4];
  float a[8];
  a[0]=blo(av.x)+blo(pv.x)+blo(qv.x); a[1]=bhi(av.x)+bhi(pv.x)+bhi(qv.x);
  a[2]=blo(av.y)+blo(pv.y)+blo(qv.y); a[3]=bhi(av.y)+bhi(pv.y)+bhi(qv.y);
  a[4]=blo(av.z)+blo(pv.z)+blo(qv.z); a[5]=bhi(av.z)+bhi(pv.z)+bhi(qv.z);
  a[6]=blo(av.w)+blo(pv.w)+blo(qv.w); a[7]=bhi(av.w)+bhi(pv.w)+bhi(qv.w);
  float s1=0.f, s2=0.f;
  #pragma unroll
  for (int k=0;k<8;++k){ s1 += a[k]; s2 += a[k]*a[k]; }
  wave_red2(s1, s2);
  float mean = s1 * (1.f/512.f);
  float var  = s2 * (1.f/512.f) - mean*mean;
  float rstd = rsqrtf(var + 1e-5f);
  float4 g0 = ((const float4*)g)[l*2], g1 = ((const float4*)g)[l*2+1];
  float4 b0 = ((const float4*)be)[l*2], b1 = ((const float4*)be)[l*2+1];
  float4 t0 = ((const float4*)tm)[l*2], t1 = ((const float4*)tm)[l*2+1];
  float r[8];
  r[0]=(a[0]-mean)*rstd*g0.x+b0.x; r[1]=(a[1]-mean)*rstd*g0.y+b0.y;
  r[2]=(a[2]-mean)*rstd*g0.z+b0.z; r[3]=(a[3]-mean)*rstd*g0.w+b0.w;
  r[4]=(a[4]-mean)*rstd*g1.x+b1.x; r[5]=(a[5]-mean)*rstd*g1.y+b1.y;
  r[6]=(a[6]-mean)*rstd*g1.z+b1.z; r[7]=(a[7]-mean)*rstd*g1.w+b1.w;
  uint4 xo; xo.x=bpack(r[0],r[1]); xo.y=bpack(r[2],r[3]); xo.z=bpack(r[4],r[5]); xo.w=bpack(r[6],r[7]);
  x1b[i4] = xo;
  float tmv[8] = {t0.x,t0.y,t0.z,t0.w,t1.x,t1.y,t1.z,t1.w};
  float dc[8], e[8];
  float dsum=0.f, esum=0.f;
  #pragma unroll
  for (int k=0;k<8;++k){
    dc[k] = sigmoidf_(r[k]*tmv[k]);
    e[k]  = expf(r[k]);
    dsum += dc[k]; esum += e[k];
  }
  uint4 dv; dv.x=bpack(dc[0],dc[1]); dv.y=bpack(dc[2],dc[3]); dv.z=bpack(dc[4],dc[5]); dv.w=bpack(dc[6],dc[7]);
  uint4 uv; uv.x=bpack(e[0]*r[0],e[1]*r[1]); uv.y=bpack(e[2]*r[2],e[3]*r[3]);
  uv.z=bpack(e[4]*r[4],e[5]*r[5]); uv.w=bpack(e[6]*r[6],e[7]*r[7]);
  dec[i4] = dv; u[i4] = uv;
  wave_red2(dsum, esum);
  if (l==0){ dm[row]=dsum*(1.f/512.f); es[row]=esum; }
}

// ---------- ln2x (wave-per-row): coupled-LN then x2-LN ----------
__global__ __launch_bounds__(256) void ln2x_k(const uint4* __restrict__ R,
    const uint4* __restrict__ V, const uint4* __restrict__ X1,
    const float* __restrict__ g1, const float* __restrict__ b1_,
    const float* __restrict__ g2, const float* __restrict__ b2_,
    uint4* __restrict__ x2b){
  const int row = blockIdx.x*4 + (threadIdx.x>>6);
  const int l = threadIdx.x & 63;
  const size_t i4 = (size_t)row*64 + l;
  uint4 rv = R[i4], vv = V[i4];
  float a[8];
  a[0]=sigmoidf_(blo(rv.x))*blo(vv.x); a[1]=sigmoidf_(bhi(rv.x))*bhi(vv.x);
  a[2]=sigmoidf_(blo(rv.y))*blo(vv.y); a[3]=sigmoidf_(bhi(rv.y))*bhi(vv.y);
  a[4]=sigmoidf_(blo(rv.z))*blo(vv.z); a[5]=sigmoidf_(bhi(rv.z))*bhi(vv.z);
  a[6]=sigmoidf_(blo(rv.w))*blo(vv.w); a[7]=sigmoidf_(bhi(rv.w))*bhi(vv.w);
  float s1=0.f, s2=0.f;
  #pragma unroll
  for (int k=0;k<8;++k){ s1 += a[k]; s2 += a[k]*a[k]; }
  wave_red2(s1, s2);
  float mean = s1*(1.f/512.f);
  float var  = s2*(1.f/512.f) - mean*mean;
  float rstd = rsqrtf(var + 1e-5f);
  float4 g10 = ((const float4*)g1)[l*2], g11 = ((const float4*)g1)[l*2+1];
  float4 b10 = ((const float4*)b1_)[l*2], b11 = ((const float4*)b1_)[l*2+1];
  float c[8];
  c[0]=(a[0]-mean)*rstd*g10.x+b10.x; c[1]=(a[1]-mean)*rstd*g10.y+b10.y;
  c[2]=(a[2]-mean)*rstd*g10.z+b10.z; c[3]=(a[3]-mean)*rstd*g10.w+b10.w;
  c[4]=(a[4]-mean)*rstd*g11.x+b11.x; c[5]=(a[5]-mean)*rstd*g11.y+b11.y;
  c[6]=(a[6]-mean)*rstd*g11.z+b11.z; c[7]=(a[7]-mean)*rstd*g11.w+b11.w;
  uint4 x1v = X1[i4];
  float t[8];
  t[0]=blo(x1v.x)+c[0]; t[1]=bhi(x1v.x)+c[1];
  t[2]=blo(x1v.y)+c[2]; t[3]=bhi(x1v.y)+c[3];
  t[4]=blo(x1v.z)+c[4]; t[5]=bhi(x1v.z)+c[5];
  t[6]=blo(x1v.w)+c[6]; t[7]=bhi(x1v.w)+c[7];
  float u1=0.f, u2=0.f;
  #pragma unroll
  for (int k=0;k<8;++k){ u1 += t[k]; u2 += t[k]*t[k]; }
  wave_red2(u1, u2);
  float mean2 = u1*(1.f/512.f);
  float var2  = u2*(1.f/512.f) - mean2*mean2;
  float rstd2 = rsqrtf(var2 + 1e-5f);
  float4 g20 = ((const float4*)g2)[l*2], g21 = ((const float4*)g2)[l*2+1];
  float4 b20 = ((const float4*)b2_)[l*2], b21 = ((const float4*)b2_)[l*2+1];
  float o[8];
  o[0]=(t[0]-mean2)*rstd2*g20.x+b20.x; o[1]=(t[1]-mean2)*rstd2*g20.y+b20.y;
  o[2]=(t[2]-mean2)*rstd2*g20.z+b20.z; o[3]=(t[3]-mean2)*rstd2*g20.w+b20.w;
  o[4]=(t[4]-mean2)*rstd2*g21.x+b21.x; o[5]=(t[5]-mean2)*rstd2*g21.y+b21.y;
  o[6]=(t[6]-mean2)*rstd2*g21.z+b21.z; o[7]=(t[7]-mean2)*rstd2*g21.w+b21.w;
  uint4 xo; xo.x=bpack(o[0],o[1]); xo.y=bpack(o[2],o[3]); xo.z=bpack(o[4],o[5]); xo.w=bpack(o[6],o[7]);
  x2b[i4] = xo;
}

// ---------- b scan phase 1 (bf16 in, 256 threads, paired) ----------
__global__ __launch_bounds__(256) void bscan_p1(const unsigned int* __restrict__ decay,
    const unsigned int* __restrict__ u, float* __restrict__ Gc, float* __restrict__ Uc){
  const int c = blockIdx.x, b = blockIdx.y, t = threadIdx.x;
  size_t base2 = ((size_t)b*SEQ + (size_t)c*CHUNK)*256 + t;
  float G0=1.f, G1=1.f, U0=0.f, U1=0.f;
  for (int i=0;i<CHUNK;++i){
    unsigned dv = decay[base2 + (size_t)i*256];
    unsigned uv = u[base2 + (size_t)i*256];
    float g0 = blo(dv), g1 = bhi(dv);
    U0 = g0*U0 + blo(uv); G0 *= g0;
    U1 = g1*U1 + bhi(uv); G1 *= g1;
  }
  size_t idx2 = ((size_t)b*NCHUNK + c)*256 + t;
  float2 gv; gv.x=G0; gv.y=G1;
  float2 uv2; uv2.x=U0; uv2.y=U1;
  ((float2*)Gc)[idx2] = gv;
  ((float2*)Uc)[idx2] = uv2;
}

// ---------- merged: b-scan phase 2 (blocks 0-3, batched prefetch) + 'a' scan ----------
__global__ __launch_bounds__(512) void scan2_k(const float* __restrict__ Gc, const float* __restrict__ Uc,
    float* __restrict__ binit, const float* __restrict__ dm, const float* __restrict__ es,
    float* __restrict__ a_out){
  __shared__ float sG[512], sU[512];
  if (blockIdx.x < 4){
    const int b = blockIdx.x, d = threadIdx.x;
    float cur = 0.f;
    for (int c0=0; c0<NCHUNK; c0+=8){
      float g[8], u[8];
      #pragma unroll
      for (int i=0;i<8;++i){
        size_t idx = ((size_t)b*NCHUNK + c0+i)*D_MODEL + d;
        g[i] = Gc[idx]; u[i] = Uc[idx];
      }
      #pragma unroll
      for (int i=0;i<8;++i){
        size_t idx = ((size_t)b*NCHUNK + c0+i)*D_MODEL + d;
        binit[idx] = cur;
        cur = g[i]*cur + u[i];
      }
    }
  } else {
    const int b = blockIdx.x - 4, tid = threadIdx.x;
    const float* dmb = dm + (size_t)b*SEQ;
    const float* esb = es + (size_t)b*SEQ;
    const int t0 = tid*4;
    float gi[4], ui[4];
    #pragma unroll
    for (int i=0;i<4;++i){ gi[i]=dmb[t0+i]; ui[i]=esb[t0+i]; }
    float G=1.f, U=0.f;
    #pragma unroll
    for (int i=0;i<4;++i){ U = gi[i]*U + ui[i]; G *= gi[i]; }
    sG[tid]=G; sU[tid]=U;
    __syncthreads();
    for (int off=1; off<512; off<<=1){
      float pg=1.f, pu=0.f;
      bool act = tid >= off;
      if (act){ pg = sG[tid-off]; pu = sU[tid-off]; }
      __syncthreads();
      if (act){ sU[tid] = sG[tid]*pu + sU[tid]; sG[tid] = sG[tid]*pg; }
      __syncthreads();
    }
    float a = (tid==0) ? 0.f : sU[tid-1];
    #pragma unroll
    for (int i=0;i<4;++i){ a = gi[i]*a + ui[i]; a_out[(size_t)b*SEQ + t0 + i] = a; }
  }
}

// ---------- p3 + LN(merged): one wave per chunk, no barriers ----------
__global__ __launch_bounds__(64) void p3ln_k(const uint4* __restrict__ decay,
    const uint4* __restrict__ u,
    const float* __restrict__ binit, const float* __restrict__ a,
    const float* __restrict__ g, const float* __restrict__ be,
    uint4* __restrict__ mb){
  const int c = blockIdx.x, b = blockIdx.y, l = threadIdx.x;
  const size_t rowBase = (size_t)b*SEQ + (size_t)c*CHUNK;   // token row
  float4 bv0 = ((const float4*)binit)[((size_t)b*NCHUNK + c)*128 + l*2];
  float4 bv1 = ((const float4*)binit)[((size_t)b*NCHUNK + c)*128 + l*2 + 1];
  float bv[8] = {bv0.x,bv0.y,bv0.z,bv0.w,bv1.x,bv1.y,bv1.z,bv1.w};
  float4 g0 = ((const float4*)g)[l*2], g1 = ((const float4*)g)[l*2+1];
  float4 b0 = ((const float4*)be)[l*2], b1 = ((const float4*)be)[l*2+1];
  float gv[8] = {g0.x,g0.y,g0.z,g0.w,g1.x,g1.y,g1.z,g1.w};
  float bb[8] = {b0.x,b0.y,b0.z,b0.w,b1.x,b1.y,b1.z,b1.w};
  for (int i=0;i<CHUNK;++i){
    size_t i4 = (rowBase + i)*64 + l;
    uint4 dv = decay[i4], uv = u[i4];
    float dc[8] = {blo(dv.x),bhi(dv.x),blo(dv.y),bhi(dv.y),blo(dv.z),bhi(dv.z),blo(dv.w),bhi(dv.w)};
    float uu[8] = {blo(uv.x),bhi(uv.x),blo(uv.y),bhi(uv.y),blo(uv.z),bhi(uv.z),blo(uv.w),bhi(uv.w)};
    float val[8];
    float av = a[rowBase + i];
    float inv = 1.f/(av + 1e-8f);
    float s1=0.f, s2=0.f;
    #pragma unroll
    for (int k=0;k<8;++k){
      bv[k] = dc[k]*bv[k] + uu[k];
      val[k] = bv[k]*inv;
      s1 += val[k]; s2 += val[k]*val[k];
    }
    wave_red2(s1, s2);
    float mean = s1*(1.f/512.f);
    float var  = s2*(1.f/512.f) - mean*mean;
    float rstd = rsqrtf(var + 1e-5f);
    uint4 mo;
    mo.x = bpack((val[0]-mean)*rstd*gv[0]+bb[0], (val[1]-mean)*rstd*gv[1]+bb[1]);
    mo.y = bpack((val[2]-mean)*rstd*gv[2]+bb[2], (val[3]-mean)*rstd*gv[3]+bb[3]);
    mo.z = bpack((val[4]-mean)*rstd*gv[4]+bb[4], (val[5]-mean)*rstd*gv[5]+bb[5]);
    mo.w = bpack((val[6]-mean)*rstd*gv[6]+bb[6], (val[7]-mean)*rstd*gv[7]+bb[7]);
    mb[i4] = mo;
  }
}

extern "C" void kernel_launch(void* const* d_in, const int* in_sizes, int n_in,
                              void* d_out, int out_size, void* d_ws, size_t ws_size,
                              hipStream_t stream){
  const float* x     = (const float*)d_in[0];
  const float* xp    = (const float*)d_in[1];
  const float* mu    = (const float*)d_in[2];
  const float* in_w  = (const float*)d_in[3];
  const float* in_b  = (const float*)d_in[4];
  const float* out_w = (const float*)d_in[5];
  const float* out_b = (const float*)d_in[6];
  const float* ln1_g = (const float*)d_in[7];
  const float* ln1_b = (const float*)d_in[8];
  const float* tm    = (const float*)d_in[9];
  const float* sm_g  = (const float*)d_in[10];
  const float* sm_b  = (const float*)d_in[11];
  const float* wr_w  = (const float*)d_in[12];
  const float* wr_b  = (const float*)d_in[13];
  const float* wv_w  = (const float*)d_in[14];
  const float* wv_b  = (const float*)d_in[15];
  const float* sc_g  = (const float*)d_in[16];
  const float* sc_b  = (const float*)d_in[17];
  const float* ln2_g = (const float*)d_in[18];
  const float* ln2_b = (const float*)d_in[19];
  const float* w1    = (const float*)d_in[20];
  const float* b1    = (const float*)d_in[21];
  const float* w2    = (const float*)d_in[22];
  const float* b2    = (const float*)d_in[23];
  const float* ln3_g = (const float*)d_in[24];
  const float* ln3_b = (const float*)d_in[25];
  float* out = (float*)d_out;
  float* ws  = (float*)d_ws;

  const size_t N = (size_t)M_TOK*D_MODEL;   // 4,194,304
  unsigned short* P0b = (unsigned short*)ws;            // proj half0 bf16 (8MB)
  unsigned short* X1b = (unsigned short*)ws + N;        // x1 bf16 (8MB)
  unsigned short* F0  = (unsigned short*)(ws + N);      // ffn2 half0 (8MB)
  unsigned short* F1  = (unsigned short*)(ws + N) + N;  // ffn2 half1 (8MB)
  unsigned short* P1b = (unsigned short*)(ws + 2*N);    // proj half1 bf16 (8MB)
  float* EX  = ws + 3*N;
  float* dm    = EX;
  float* es    = EX + 8192;
  float* aarr  = EX + 16384;
  float* Gc    = EX + 24576;
  float* Uc    = Gc + 131072;
  float* binit = Uc + 131072;

  unsigned short* SB = (unsigned short*)(ws + 3*N + N/4);
  unsigned short* Wq = SB;
  unsigned short* Wo = Wq + 786432;
  unsigned short* Wr = Wo + 262144;
  unsigned short* Wv = Wr + 262144;
  unsigned short* W1 = Wv + 262144;
  unsigned short* W2 = W1 + 1048576;
  unsigned short* Xb = W2 + 1048576;       // shifted bf16, later x2 bf16
  unsigned short* Mb = Xb + N;             // merged bf16
  unsigned short* U  = Mb + N;
  unsigned short* Qb  = U;                 // qkv bf16 (24MB)
  unsigned short* AOb = U + 12*1024*1024;  // attn out bf16 (8MB)
  unsigned short* ub   = U;                // after Qb dead
  unsigned short* decb = U + 12*1024*1024; // after AOb dead
  unsigned short* Rb   = U;                // after ub dead
  unsigned short* Vb   = U + 4*1024*1024;
  unsigned short* Hb   = U;                // FFN hidden (32MB)

  // 0. weight converts + shift (bf16 only)
  cvtshift_k<<<7680, 256, 0, stream>>>(in_w, out_w, wr_w, wv_w, w1, w2,
                                       Wq, Wo, Wr, Wv, W1, W2,
                                       x, xp, mu, Xb);
  // 1. qkv -> Qb
  mgemm_k<0,1><<<dim3(12,64), 256, 0, stream>>>(Xb, Wq, in_b, nullptr, Qb, 1536, 512);
  // 2. flash attention -> AOb
  fattn_k<<<dim3(SEQ/128, NH, BATCH), 512, 0, stream>>>(Qb, AOb);
  // 3. out-proj split-K -> P0b (bias) + P1b
  mgemm64_k<0,0,1><<<dim3(16,64), 256, 0, stream>>>(AOb, Wo, nullptr, out_b, nullptr,
                                                    P0b, P1b, 512, 512);
  // 4. x1 = LN(shifted + P0 + P1) -> X1b; decb/ub; dm/es  (wave-per-row)
  ln_scan_k<<<M_TOK/4, 256, 0, stream>>>((const uint4*)Xb, (const uint4*)P0b,
                                         (const uint4*)P1b,
                                         ln1_g, ln1_b, tm,
                                         (uint4*)X1b, (uint4*)decb, (uint4*)ub,
                                         dm, es);
  // 5. b-scan phase 1
  bscan_p1<<<dim3(NCHUNK, BATCH), 256, 0, stream>>>((const unsigned int*)decb, (const unsigned int*)ub, Gc, Uc);
  // 6. merged p2 (batched prefetch) + ascan
  scan2_k<<<8, 512, 0, stream>>>(Gc, Uc, binit, dm, es, aarr);
  // 7. p3 + LN(merged) -> Mb  (one wave per chunk)
  p3ln_k<<<dim3(NCHUNK, BATCH), 64, 0, stream>>>((const uint4*)decb, (const uint4*)ub,
                                                 binit, aarr, sm_g, sm_b, (uint4*)Mb);
  // 8. r -> Rb, v -> Vb (bf16, fused)
  mgemm64_k<0,1,0><<<dim3(16,64), 256, 0, stream>>>(Mb, Wr, Wv, wr_b, wv_b,
                                                    Rb, Vb, 512, 512);
  // 9. coupled-LN + x2-LN -> Xb (x2 bf16)  (wave-per-row)
  ln2x_k<<<M_TOK/4, 256, 0, stream>>>((const uint4*)Rb, (const uint4*)Vb,
                                      (const uint4*)X1b,
                                      sc_g, sc_b, ln2_g, ln2_b, (uint4*)Xb);
  // 10. hidden = relu(x2 @ w1.T + b1) -> Hb
  mgemm_k<1,1><<<dim3(16,64), 256, 0, stream>>>(Xb, W1, b1, nullptr, Hb, 2048, 512);
  // 11. ffnout split-K -> F0 (bias) + F1
  mgemm64_k<0,0,1><<<dim3(16,64), 256, 0, stream>>>(Hb, W2, nullptr, b2, nullptr,
                                                    F0, F1, 512, 2048);
  // 12. out = LN(x2 + F0 + F1)  (wave-per-row)
  lnfin_k<<<M_TOK/4, 256, 0, stream>>>((const uint4*)Xb, (const uint4*)F0,
                                       (const uint4*)F1, ln3_g, ln3_b, out);
}

// Round 15
// 228.028 us; speedup vs baseline: 1.1520x; 1.0433x over previous
//
#include <hip/hip_runtime.h>
#include <math.h>

#define D_MODEL 512
#define SEQ     2048
#define BATCH   4
#define NH      8
#define HD      64
#define CHUNK   16
#define NCHUNK  128
#define M_TOK   (BATCH*SEQ)   // 8192

typedef __attribute__((ext_vector_type(8))) short bhalf8;   // 8 bf16 = 4 VGPR
typedef __attribute__((ext_vector_type(4))) float f32x4;

#define LOG2E 1.4426950408889634f

__device__ __forceinline__ unsigned short f2b(float f){   // fp32 -> bf16 RNE
  unsigned u = __float_as_uint(f);
  u += 0x7FFFu + ((u>>16)&1u);
  return (unsigned short)(u>>16);
}
__device__ __forceinline__ float b2f(unsigned short h){
  return __uint_as_float(((unsigned)h)<<16);
}
__device__ __forceinline__ float blo(unsigned v){ return __uint_as_float(v<<16); }
__device__ __forceinline__ float bhi(unsigned v){ return __uint_as_float(v & 0xFFFF0000u); }
__device__ __forceinline__ unsigned bpack(float a, float b){
  return (unsigned)f2b(a) | ((unsigned)f2b(b)<<16);
}

__device__ __forceinline__ void gll16(const void* g, void* l){
  __builtin_amdgcn_global_load_lds(
      (const __attribute__((address_space(1))) unsigned int*)g,
      (__attribute__((address_space(3))) unsigned int*)l, 16, 0, 0);
}

__device__ __forceinline__ float exp2_hw(float x){
  float r;
  asm volatile("v_exp_f32 %0, %1" : "=v"(r) : "v"(x));
  return r;
}
__device__ __forceinline__ float exp_hw(float x){ return exp2_hw(x*LOG2E); }
__device__ __forceinline__ float sig_hw(float x){
  return 1.f/(1.f + exp2_hw(-LOG2E*x));
}

// ---------- wave-level paired reduction (64 lanes, no barriers/LDS) ----------
__device__ __forceinline__ void wave_red2(float& a, float& b){
  #pragma unroll
  for (int o=32;o>0;o>>=1){ a += __shfl_xor(a,o); b += __shfl_xor(b,o); }
}

// ---------- merged: weight converts + shift (bf16 out only) ----------
__global__ void cvtshift_k(const float* __restrict__ s0,const float* __restrict__ s1,
                           const float* __restrict__ s2,const float* __restrict__ s3,
                           const float* __restrict__ s4,const float* __restrict__ s5,
                           unsigned short* __restrict__ d0,unsigned short* __restrict__ d1,
                           unsigned short* __restrict__ d2,unsigned short* __restrict__ d3,
                           unsigned short* __restrict__ d4,unsigned short* __restrict__ d5,
                           const float* __restrict__ x, const float* __restrict__ xp,
                           const float* __restrict__ mu,
                           unsigned short* __restrict__ ob){
  int t = blockIdx.x*blockDim.x + threadIdx.x;
  if (t < 917504){
    int j = t;
    const float* s; unsigned short* d;
    if (j < 196608){ s=s0; d=d0; }
    else if ((j-=196608) < 65536){ s=s1; d=d1; }
    else if ((j-=65536)  < 65536){ s=s2; d=d2; }
    else if ((j-=65536)  < 65536){ s=s3; d=d3; }
    else if ((j-=65536)  < 262144){ s=s4; d=d4; }
    else { j-=262144; s=s5; d=d5; }
    float4 v = ((const float4*)s)[j];
    uint2 p; p.x = bpack(v.x, v.y); p.y = bpack(v.z, v.w);
    ((uint2*)d)[j] = p;
  } else {
    int i = t - 917504;   // 0 .. 1048575
    float m = mu[0];
    float4 a = ((const float4*)x)[i], p = ((const float4*)xp)[i];
    float4 r;
    r.x = m*a.x + (1.f-m)*p.x; r.y = m*a.y + (1.f-m)*p.y;
    r.z = m*a.z + (1.f-m)*p.z; r.w = m*a.w + (1.f-m)*p.w;
    uint2 q; q.x = bpack(r.x, r.y); q.y = bpack(r.z, r.w);
    ((uint2*)ob)[i] = q;
  }
}

// ---------- bf16 MFMA GEMM 128x128, XCD-swizzled ----------
template<int ACT, int OUTB>
__global__ __launch_bounds__(256) void mgemm_k(const unsigned short* __restrict__ A,
    const unsigned short* __restrict__ W, const float* __restrict__ bias,
    float* __restrict__ Yf, unsigned short* __restrict__ Yb, int Nd, int K){
  __shared__ unsigned short As[128*64];
  __shared__ unsigned short Bs[128*64];
  const int tid = threadIdx.x;
  const int w = tid>>6, lane = tid&63;
  const int l15 = lane&15, l4 = lane>>4;
  const int wr = w>>1, wc = w&1;
  const int nwg = gridDim.x*gridDim.y;
  const int orig = blockIdx.y*gridDim.x + blockIdx.x;
  const int swz = (orig&7)*(nwg>>3) + (orig>>3);
  const int bn = swz % gridDim.x;
  const int bm = swz / gridDim.x;

  const size_t Kb = (size_t)K*2;
  const int srow  = lane>>3;
  const int sbyte = ((lane&7)*16) ^ (srow<<4);
  const char* Ag = (const char*)A + (size_t)(bm*128)*Kb + sbyte;
  const char* Wg = (const char*)W + (size_t)(bn*128)*Kb + sbyte;

  f32x4 acc[4][4];
  const f32x4 z = {0.f,0.f,0.f,0.f};
  #pragma unroll
  for (int i=0;i<4;++i)
    #pragma unroll
    for (int j=0;j<4;++j) acc[i][j] = z;

  const int KT = K/64;
  for (int kt=0; kt<KT; ++kt){
    if (kt) __syncthreads();
    const size_t kOff = (size_t)kt*128;
    #pragma unroll
    for (int i=0;i<4;++i){
      int c = w*4 + i;
      int r = c*8 + srow;
      gll16(Ag + (size_t)r*Kb + kOff, (char*)As + c*1024);
      gll16(Wg + (size_t)r*Kb + kOff, (char*)Bs + c*1024);
    }
    __syncthreads();

    bhalf8 af[4][2], bf_[4][2];
    #pragma unroll
    for (int fr=0; fr<4; ++fr){
      int row = wr*64 + fr*16 + l15;
      #pragma unroll
      for (int ks=0; ks<2; ++ks){
        int byo = (l4*16 + ks*64) ^ ((row&7)<<4);
        af[fr][ks] = *(const bhalf8*)((const char*)As + row*128 + byo);
      }
    }
    #pragma unroll
    for (int fc=0; fc<4; ++fc){
      int row = wc*64 + fc*16 + l15;
      #pragma unroll
      for (int ks=0; ks<2; ++ks){
        int byo = (l4*16 + ks*64) ^ ((row&7)<<4);
        bf_[fc][ks] = *(const bhalf8*)((const char*)Bs + row*128 + byo);
      }
    }
    #pragma unroll
    for (int ks=0; ks<2; ++ks)
      #pragma unroll
      for (int fr=0; fr<4; ++fr)
        #pragma unroll
        for (int fc=0; fc<4; ++fc)
          acc[fr][fc] = __builtin_amdgcn_mfma_f32_16x16x32_bf16(af[fr][ks], bf_[fc][ks], acc[fr][fc], 0, 0, 0);
  }

  const int rowBase = bm*128 + wr*64;
  const int colBase = bn*128 + wc*64;
  #pragma unroll
  for (int fc=0; fc<4; ++fc){
    int col = colBase + fc*16 + l15;
    float bv = bias[col];
    #pragma unroll
    for (int fr=0; fr<4; ++fr){
      #pragma unroll
      for (int j=0; j<4; ++j){
        int row = rowBase + fr*16 + l4*4 + j;
        float v = acc[fr][fc][j] + bv;
        if (ACT) v = fmaxf(v, 0.f);
        if (OUTB) Yb[(size_t)row*Nd + col] = f2b(v);
        else      Yf[(size_t)row*Nd + col] = v;
      }
    }
  }
}

// ---------- bf16 MFMA GEMM 128x64, XCD-swizzled; FUSE2 or SPLITK ----------
template<int ACT, int FUSE2, int SPLITK>
__global__ __launch_bounds__(256) void mgemm64_k(const unsigned short* __restrict__ A,
    const unsigned short* __restrict__ W0, const unsigned short* __restrict__ W1v,
    const float* __restrict__ bias0, const float* __restrict__ bias1,
    unsigned short* __restrict__ Yb0, unsigned short* __restrict__ Yb1,
    int Nd, int K){
  __shared__ unsigned short As[128*64];
  __shared__ unsigned short Bs[64*64];
  const int tid = threadIdx.x;
  const int w = tid>>6, lane = tid&63;
  const int l15 = lane&15, l4 = lane>>4;
  const int wr = w>>1, wc = w&1;
  const int nwg = gridDim.x*gridDim.y;
  const int orig = blockIdx.y*gridDim.x + blockIdx.x;
  const int swz = (orig&7)*(nwg>>3) + (orig>>3);
  int bn = swz % gridDim.x;
  const int bm = swz / gridDim.x;
  const unsigned short* W = W0;
  const float* bias = bias0;
  unsigned short* Yb = Yb0;
  int half = 0;
  if (FUSE2 && bn >= 8){ W = W1v; bias = bias1; Yb = Yb1; bn -= 8; }
  if (SPLITK && bn >= 8){ half = 1; Yb = Yb1; bn -= 8; }

  const int Ksr = SPLITK ? (K>>1) : K;
  const size_t Kb = (size_t)K*2;
  const size_t hOff = (size_t)half * Ksr * 2;
  const int srow  = lane>>3;
  const int sbyte = ((lane&7)*16) ^ (srow<<4);
  const char* Ag = (const char*)A + (size_t)(bm*128)*Kb + hOff + sbyte;
  const char* Wg = (const char*)W + (size_t)(bn*64)*Kb + hOff + sbyte;

  f32x4 acc[4][2];
  const f32x4 z = {0.f,0.f,0.f,0.f};
  #pragma unroll
  for (int i=0;i<4;++i)
    #pragma unroll
    for (int j=0;j<2;++j) acc[i][j] = z;

  const int KT = Ksr/64;
  for (int kt=0; kt<KT; ++kt){
    if (kt) __syncthreads();
    const size_t kOff = (size_t)kt*128;
    #pragma unroll
    for (int i=0;i<4;++i){
      int c = w*4 + i;
      int r = c*8 + srow;
      gll16(Ag + (size_t)r*Kb + kOff, (char*)As + c*1024);
    }
    #pragma unroll
    for (int i=0;i<2;++i){
      int c = w*2 + i;
      int r = c*8 + srow;
      gll16(Wg + (size_t)r*Kb + kOff, (char*)Bs + c*1024);
    }
    __syncthreads();

    bhalf8 af[4][2], bf_[2][2];
    #pragma unroll
    for (int fr=0; fr<4; ++fr){
      int row = wr*64 + fr*16 + l15;
      #pragma unroll
      for (int ks=0; ks<2; ++ks){
        int byo = (l4*16 + ks*64) ^ ((row&7)<<4);
        af[fr][ks] = *(const bhalf8*)((const char*)As + row*128 + byo);
      }
    }
    #pragma unroll
    for (int fc=0; fc<2; ++fc){
      int row = wc*32 + fc*16 + l15;
      #pragma unroll
      for (int ks=0; ks<2; ++ks){
        int byo = (l4*16 + ks*64) ^ ((row&7)<<4);
        bf_[fc][ks] = *(const bhalf8*)((const char*)Bs + row*128 + byo);
      }
    }
    #pragma unroll
    for (int ks=0; ks<2; ++ks)
      #pragma unroll
      for (int fr=0; fr<4; ++fr)
        #pragma unroll
        for (int fc=0; fc<2; ++fc)
          acc[fr][fc] = __builtin_amdgcn_mfma_f32_16x16x32_bf16(af[fr][ks], bf_[fc][ks], acc[fr][fc], 0, 0, 0);
  }

  const int rowBase = bm*128 + wr*64;
  const int colBase = bn*64 + wc*32;
  #pragma unroll
  for (int fc=0; fc<2; ++fc){
    int col = colBase + fc*16 + l15;
    float bv = (SPLITK && half) ? 0.f : bias[col];
    #pragma unroll
    for (int fr=0; fr<4; ++fr){
      #pragma unroll
      for (int j=0; j<4; ++j){
        int row = rowBase + fr*16 + l4*4 + j;
        float v = acc[fr][fc][j] + bv;
        if (ACT) v = fmaxf(v, 0.f);
        Yb[(size_t)row*Nd + col] = f2b(v);
      }
    }
  }
}

// ---------- bf16 MFMA flash attention (known-good 71us version) ----------
__global__ __launch_bounds__(512, 4) void fattn_k(const unsigned short* __restrict__ qkv,
                                                  unsigned short* __restrict__ ao){
  __shared__ unsigned short Ks[2][64*64];
  __shared__ unsigned short Vt[2][64*64];
  __shared__ unsigned short Ps[128*64];
  const int nwg = gridDim.x*gridDim.y*gridDim.z;   // 512
  const int orig = (blockIdx.z*gridDim.y + blockIdx.y)*gridDim.x + blockIdx.x;
  const int swz = (orig&7)*(nwg>>3) + (orig>>3);
  const int qt = swz % gridDim.x;
  const int rem = swz / gridDim.x;
  const int h = rem % gridDim.y;
  const int b = rem / gridDim.y;
  const int tid = threadIdx.x, w = tid>>6, lane = tid&63;
  const int l15 = lane&15, l4 = lane>>4;
  const size_t rowB = 3072;
  const char* base = (const char*)qkv + (size_t)b*SEQ*rowB;
  const char* Kg = base + 1024 + h*128;
  const char* Vg = base + 2048 + h*128;
  const float C2 = 0.18033688f;             // 0.125 * log2(e)

  bhalf8 qf[2];
  {
    const char* qrow = base + (size_t)(qt*128 + w*16 + l15)*rowB + h*128;
    qf[0] = *(const bhalf8*)(qrow + l4*16);
    qf[1] = *(const bhalf8*)(qrow + l4*16 + 64);
  }
  bhalf8 v1;
  {
    short o = (l15==0) ? (short)0x3F80 : (short)0;
    v1 = (bhalf8){o,o,o,o,o,o,o,o};
  }

  const f32x4 z = {0.f,0.f,0.f,0.f};
  f32x4 oa[4], ol = z;
  #pragma unroll
  for (int i=0;i<4;++i) oa[i] = z;
  float mj = -INFINITY;

  const int srow  = lane>>3;
  const int sbyte = ((lane&7)*16) ^ (srow<<4);
  const int vd = lane;
  const int vsel = (vd>>3)&1;

  unsigned short vload[8];
  {
    int r = w*8 + srow;
    gll16(Kg + (size_t)r*rowB + sbyte, (char*)Ks[0] + w*1024);
  }
  #pragma unroll
  for (int i=0;i<8;++i)
    vload[i] = *(const unsigned short*)(Vg + (size_t)(w*8 + i)*rowB + vd*2);

  int cur = 0;
  for (int kt=0; kt<SEQ/64; ++kt){
    #pragma unroll
    for (int i=0;i<2;++i){
      int p = i ^ vsel;
      unsigned lo = (unsigned)vload[p*4+0] | ((unsigned)vload[p*4+1]<<16);
      unsigned hi = (unsigned)vload[p*4+2] | ((unsigned)vload[p*4+3]<<16);
      uint2 pk; pk.x = lo; pk.y = hi;
      int byo = (w*16 + p*8) ^ ((vd&7)<<4);
      *(uint2*)((char*)Vt[cur] + vd*128 + byo) = pk;
    }
    __syncthreads();

    if (kt+1 < SEQ/64){
      int r = w*8 + srow;
      gll16(Kg + (size_t)((kt+1)*64 + r)*rowB + sbyte, (char*)Ks[cur^1] + w*1024);
      #pragma unroll
      for (int i=0;i<8;++i)
        vload[i] = *(const unsigned short*)(Vg + (size_t)((kt+1)*64 + w*8 + i)*rowB + vd*2);
    }

    bhalf8 kf[4][2];
    #pragma unroll
    for (int fc=0; fc<4; ++fc){
      int kr = fc*16 + l15;
      #pragma unroll
      for (int ks=0; ks<2; ++ks){
        int byo = (l4*16 + ks*64) ^ ((kr&7)<<4);
        kf[fc][ks] = *(const bhalf8*)((const char*)Ks[cur] + kr*128 + byo);
      }
    }
    f32x4 s[4];
    #pragma unroll
    for (int i=0;i<4;++i) s[i] = z;
    __builtin_amdgcn_s_setprio(1);
    #pragma unroll
    for (int ks=0; ks<2; ++ks)
      #pragma unroll
      for (int fc=0; fc<4; ++fc)
        s[fc] = __builtin_amdgcn_mfma_f32_16x16x32_bf16(kf[fc][ks], qf[ks], s[fc], 0, 0, 0);
    __builtin_amdgcn_s_setprio(0);

    {
      float rm0 = fmaxf(fmaxf(s[0][0],s[0][1]), fmaxf(s[0][2],s[0][3]));
      float rm1 = fmaxf(fmaxf(s[1][0],s[1][1]), fmaxf(s[1][2],s[1][3]));
      float rm2 = fmaxf(fmaxf(s[2][0],s[2][1]), fmaxf(s[2][2],s[2][3]));
      float rm3 = fmaxf(fmaxf(s[3][0],s[3][1]), fmaxf(s[3][2],s[3][3]));
      float rm = fmaxf(fmaxf(rm0,rm1), fmaxf(rm2,rm3));
      rm = fmaxf(rm, __shfl_xor(rm,16));
      rm = fmaxf(rm, __shfl_xor(rm,32));
      float tmax = rm * C2;
      if (__any(tmax > mj + 8.f)){
        float mn = fmaxf(mj, tmax);
        float sc = exp2_hw(mj - mn);
        mj = mn;
        float scj0 = __shfl(sc, l4*4+0), scj1 = __shfl(sc, l4*4+1);
        float scj2 = __shfl(sc, l4*4+2), scj3 = __shfl(sc, l4*4+3);
        #pragma unroll
        for (int fc=0; fc<4; ++fc){
          oa[fc][0] *= scj0; oa[fc][1] *= scj1;
          oa[fc][2] *= scj2; oa[fc][3] *= scj3;
        }
        ol[0] *= scj0; ol[1] *= scj1; ol[2] *= scj2; ol[3] *= scj3;
      }
      int qrow = w*16 + l15;
      #pragma unroll
      for (int fc=0; fc<4; ++fc){
        float p0 = exp2_hw(fmaf(C2, s[fc][0], -mj));
        float p1 = exp2_hw(fmaf(C2, s[fc][1], -mj));
        float p2 = exp2_hw(fmaf(C2, s[fc][2], -mj));
        float p3 = exp2_hw(fmaf(C2, s[fc][3], -mj));
        unsigned lo, hi;
        asm volatile("v_cvt_pk_bf16_f32 %0, %1, %2" : "=v"(lo) : "v"(p0), "v"(p1));
        asm volatile("v_cvt_pk_bf16_f32 %0, %1, %2" : "=v"(hi) : "v"(p2), "v"(p3));
        uint2 pk; pk.x = lo; pk.y = hi;
        int byo = (fc*32 + l4*8) ^ ((l15&7)<<4);
        *(uint2*)((char*)Ps + qrow*128 + byo) = pk;
      }
    }

    bhalf8 vf[4][2];
    #pragma unroll
    for (int fc=0; fc<4; ++fc){
      int d = fc*16 + l15;
      #pragma unroll
      for (int ks=0; ks<2; ++ks){
        int byo = (ks*64 + l4*16) ^ ((d&7)<<4);
        vf[fc][ks] = *(const bhalf8*)((const char*)Vt[cur] + d*128 + byo);
      }
    }
    {
      int qrow = w*16 + l15;
      bhalf8 pf[2];
      #pragma unroll
      for (int ks=0; ks<2; ++ks){
        int byo = (ks*64 + l4*16) ^ ((l15&7)<<4);
        pf[ks] = *(const bhalf8*)((const char*)Ps + qrow*128 + byo);
      }
      __builtin_amdgcn_s_setprio(1);
      #pragma unroll
      for (int ks=0; ks<2; ++ks){
        #pragma unroll
        for (int fc=0; fc<4; ++fc)
          oa[fc] = __builtin_amdgcn_mfma_f32_16x16x32_bf16(pf[ks], vf[fc][ks], oa[fc], 0, 0, 0);
        ol = __builtin_amdgcn_mfma_f32_16x16x32_bf16(pf[ks], v1, ol, 0, 0, 0);
      }
      __builtin_amdgcn_s_setprio(0);
    }
    cur ^= 1;
  }

  {
    float li[4];
    #pragma unroll
    for (int j=0;j<4;++j) li[j] = 1.f/__shfl(ol[j], l4<<4);
    #pragma unroll
    for (int fc=0; fc<4; ++fc){
      int col = h*64 + fc*16 + l15;
      size_t r0 = (size_t)(b*SEQ + qt*128 + w*16 + l4*4);
      ao[(r0+0)*D_MODEL + col] = f2b(oa[fc][0]*li[0]);
      ao[(r0+1)*D_MODEL + col] = f2b(oa[fc][1]*li[1]);
      ao[(r0+2)*D_MODEL + col] = f2b(oa[fc][2]*li[2]);
      ao[(r0+3)*D_MODEL + col] = f2b(oa[fc][3]*li[3]);
    }
  }
}

// ---------- final LN (wave-per-row): out = LN(x2b + F0 + F1), fp32 out ----------
__global__ __launch_bounds__(256) void lnfin_k(const uint4* __restrict__ X2b,
    const uint4* __restrict__ F0, const uint4* __restrict__ F1,
    const float* __restrict__ g, const float* __restrict__ be, float* __restrict__ outf){
  const int row = blockIdx.x*4 + (threadIdx.x>>6);
  const int l = threadIdx.x & 63;
  const size_t i4 = (size_t)row*64 + l;
  uint4 xv = X2b[i4], f0 = F0[i4], f1 = F1[i4];
  float a[8];
  a[0]=blo(xv.x)+blo(f0.x)+blo(f1.x); a[1]=bhi(xv.x)+bhi(f0.x)+bhi(f1.x);
  a[2]=blo(xv.y)+blo(f0.y)+blo(f1.y); a[3]=bhi(xv.y)+bhi(f0.y)+bhi(f1.y);
  a[4]=blo(xv.z)+blo(f0.z)+blo(f1.z); a[5]=bhi(xv.z)+bhi(f0.z)+bhi(f1.z);
  a[6]=blo(xv.w)+blo(f0.w)+blo(f1.w); a[7]=bhi(xv.w)+bhi(f0.w)+bhi(f1.w);
  float s1=0.f, s2=0.f;
  #pragma unroll
  for (int k=0;k<8;++k){ s1 += a[k]; s2 += a[k]*a[k]; }
  wave_red2(s1, s2);
  float mean = s1 * (1.f/512.f);
  float var  = s2 * (1.f/512.f) - mean*mean;
  float rstd = rsqrtf(var + 1e-5f);
  float4 g0 = ((const float4*)g)[l*2], g1 = ((const float4*)g)[l*2+1];
  float4 b0 = ((const float4*)be)[l*2], b1 = ((const float4*)be)[l*2+1];
  float4 r0, r1;
  r0.x=(a[0]-mean)*rstd*g0.x+b0.x; r0.y=(a[1]-mean)*rstd*g0.y+b0.y;
  r0.z=(a[2]-mean)*rstd*g0.z+b0.z; r0.w=(a[3]-mean)*rstd*g0.w+b0.w;
  r1.x=(a[4]-mean)*rstd*g1.x+b1.x; r1.y=(a[5]-mean)*rstd*g1.y+b1.y;
  r1.z=(a[6]-mean)*rstd*g1.z+b1.z; r1.w=(a[7]-mean)*rstd*g1.w+b1.w;
  ((float4*)outf)[(size_t)row*128 + l*2]     = r0;
  ((float4*)outf)[(size_t)row*128 + l*2 + 1] = r1;
}

// ---------- ln_scan (wave-per-row): x1=LN(shift+P0+P1); scan prep ----------
__global__ __launch_bounds__(256) void ln_scan_k(const uint4* __restrict__ Ab,
    const uint4* __restrict__ P0, const uint4* __restrict__ P1,
    const float* __restrict__ g, const float* __restrict__ be, const float* __restrict__ tm,
    uint4* __restrict__ x1b, uint4* __restrict__ dec, uint4* __restrict__ u,
    float* __restrict__ dm, float* __restrict__ es){
  const int row = blockIdx.x*4 + (threadIdx.x>>6);
  const int l = threadIdx.x & 63;
  const size_t i4 = (size_t)row*64 + l;
  uint4 av = Ab[i4], pv = P0[i4], qv = P1[i4];
  float a[8];
  a[0]=blo(av.x)+blo(pv.x)+blo(qv.x); a[1]=bhi(av.x)+bhi(pv.x)+bhi(qv.x);
  a[2]=blo(av.y)+blo(pv.y)+blo(qv.y); a[3]=bhi(av.y)+bhi(pv.y)+bhi(qv.y);
  a[4]=blo(av.z)+blo(pv.z)+blo(qv.z); a[5]=bhi(av.z)+bhi(pv.z)+bhi(qv.z);
  a[6]=blo(av.w)+blo(pv.w)+blo(qv.w); a[7]=bhi(av.w)+bhi(pv.w)+bhi(qv.w);
  float s1=0.f, s2=0.f;
  #pragma unroll
  for (int k=0;k<8;++k){ s1 += a[k]; s2 += a[k]*a[k]; }
  wave_red2(s1, s2);
  float mean = s1 * (1.f/512.f);
  float var  = s2 * (1.f/512.f) - mean*mean;
  float rstd = rsqrtf(var + 1e-5f);
  float4 g0 = ((const float4*)g)[l*2], g1 = ((const float4*)g)[l*2+1];
  float4 b0 = ((const float4*)be)[l*2], b1 = ((const float4*)be)[l*2+1];
  float4 t0 = ((const float4*)tm)[l*2], t1 = ((const float4*)tm)[l*2+1];
  float r[8];
  r[0]=(a[0]-mean)*rstd*g0.x+b0.x; r[1]=(a[1]-mean)*rstd*g0.y+b0.y;
  r[2]=(a[2]-mean)*rstd*g0.z+b0.z; r[3]=(a[3]-mean)*rstd*g0.w+b0.w;
  r[4]=(a[4]-mean)*rstd*g1.x+b1.x; r[5]=(a[5]-mean)*rstd*g1.y+b1.y;
  r[6]=(a[6]-mean)*rstd*g1.z+b1.z; r[7]=(a[7]-mean)*rstd*g1.w+b1.w;
  uint4 xo; xo.x=bpack(r[0],r[1]); xo.y=bpack(r[2],r[3]); xo.z=bpack(r[4],r[5]); xo.w=bpack(r[6],r[7]);
  x1b[i4] = xo;
  float tmv[8] = {t0.x,t0.y,t0.z,t0.w,t1.x,t1.y,t1.z,t1.w};
  float dc[8], e[8];
  float dsum=0.f, esum=0.f;
  #pragma unroll
  for (int k=0;k<8;++k){
    dc[k] = sig_hw(r[k]*tmv[k]);
    e[k]  = exp_hw(r[k]);
    dsum += dc[k]; esum += e[k];
  }
  uint4 dv; dv.x=bpack(dc[0],dc[1]); dv.y=bpack(dc[2],dc[3]); dv.z=bpack(dc[4],dc[5]); dv.w=bpack(dc[6],dc[7]);
  uint4 uv; uv.x=bpack(e[0]*r[0],e[1]*r[1]); uv.y=bpack(e[2]*r[2],e[3]*r[3]);
  uv.z=bpack(e[4]*r[4],e[5]*r[5]); uv.w=bpack(e[6]*r[6],e[7]*r[7]);
  dec[i4] = dv; u[i4] = uv;
  wave_red2(dsum, esum);
  if (l==0){ dm[row]=dsum*(1.f/512.f); es[row]=esum; }
}

// ---------- ln2x (wave-per-row): coupled-LN then x2-LN ----------
__global__ __launch_bounds__(256) void ln2x_k(const uint4* __restrict__ R,
    const uint4* __restrict__ V, const uint4* __restrict__ X1,
    const float* __restrict__ g1, const float* __restrict__ b1_,
    const float* __restrict__ g2, const float* __restrict__ b2_,
    uint4* __restrict__ x2b){
  const int row = blockIdx.x*4 + (threadIdx.x>>6);
  const int l = threadIdx.x & 63;
  const size_t i4 = (size_t)row*64 + l;
  uint4 rv = R[i4], vv = V[i4];
  float a[8];
  a[0]=sig_hw(blo(rv.x))*blo(vv.x); a[1]=sig_hw(bhi(rv.x))*bhi(vv.x);
  a[2]=sig_hw(blo(rv.y))*blo(vv.y); a[3]=sig_hw(bhi(rv.y))*bhi(vv.y);
  a[4]=sig_hw(blo(rv.z))*blo(vv.z); a[5]=sig_hw(bhi(rv.z))*bhi(vv.z);
  a[6]=sig_hw(blo(rv.w))*blo(vv.w); a[7]=sig_hw(bhi(rv.w))*bhi(vv.w);
  float s1=0.f, s2=0.f;
  #pragma unroll
  for (int k=0;k<8;++k){ s1 += a[k]; s2 += a[k]*a[k]; }
  wave_red2(s1, s2);
  float mean = s1*(1.f/512.f);
  float var  = s2*(1.f/512.f) - mean*mean;
  float rstd = rsqrtf(var + 1e-5f);
  float4 g10 = ((const float4*)g1)[l*2], g11 = ((const float4*)g1)[l*2+1];
  float4 b10 = ((const float4*)b1_)[l*2], b11 = ((const float4*)b1_)[l*2+1];
  float c[8];
  c[0]=(a[0]-mean)*rstd*g10.x+b10.x; c[1]=(a[1]-mean)*rstd*g10.y+b10.y;
  c[2]=(a[2]-mean)*rstd*g10.z+b10.z; c[3]=(a[3]-mean)*rstd*g10.w+b10.w;
  c[4]=(a[4]-mean)*rstd*g11.x+b11.x; c[5]=(a[5]-mean)*rstd*g11.y+b11.y;
  c[6]=(a[6]-mean)*rstd*g11.z+b11.z; c[7]=(a[7]-mean)*rstd*g11.w+b11.w;
  uint4 x1v = X1[i4];
  float t[8];
  t[0]=blo(x1v.x)+c[0]; t[1]=bhi(x1v.x)+c[1];
  t[2]=blo(x1v.y)+c[2]; t[3]=bhi(x1v.y)+c[3];
  t[4]=blo(x1v.z)+c[4]; t[5]=bhi(x1v.z)+c[5];
  t[6]=blo(x1v.w)+c[6]; t[7]=bhi(x1v.w)+c[7];
  float u1=0.f, u2=0.f;
  #pragma unroll
  for (int k=0;k<8;++k){ u1 += t[k]; u2 += t[k]*t[k]; }
  wave_red2(u1, u2);
  float mean2 = u1*(1.f/512.f);
  float var2  = u2*(1.f/512.f) - mean2*mean2;
  float rstd2 = rsqrtf(var2 + 1e-5f);
  float4 g20 = ((const float4*)g2)[l*2], g21 = ((const float4*)g2)[l*2+1];
  float4 b20 = ((const float4*)b2_)[l*2], b21 = ((const float4*)b2_)[l*2+1];
  float o[8];
  o[0]=(t[0]-mean2)*rstd2*g20.x+b20.x; o[1]=(t[1]-mean2)*rstd2*g20.y+b20.y;
  o[2]=(t[2]-mean2)*rstd2*g20.z+b20.z; o[3]=(t[3]-mean2)*rstd2*g20.w+b20.w;
  o[4]=(t[4]-mean2)*rstd2*g21.x+b21.x; o[5]=(t[5]-mean2)*rstd2*g21.y+b21.y;
  o[6]=(t[6]-mean2)*rstd2*g21.z+b21.z; o[7]=(t[7]-mean2)*rstd2*g21.w+b21.w;
  uint4 xo; xo.x=bpack(o[0],o[1]); xo.y=bpack(o[2],o[3]); xo.z=bpack(o[4],o[5]); xo.w=bpack(o[6],o[7]);
  x2b[i4] = xo;
}

// ---------- b scan phase 1 (bf16 in, CHUNK=16) ----------
__global__ __launch_bounds__(256) void bscan_p1(const unsigned int* __restrict__ decay,
    const unsigned int* __restrict__ u, float* __restrict__ Gc, float* __restrict__ Uc){
  const int c = blockIdx.x, b = blockIdx.y, t = threadIdx.x;
  size_t base2 = ((size_t)b*SEQ + (size_t)c*CHUNK)*256 + t;
  float G0=1.f, G1=1.f, U0=0.f, U1=0.f;
  for (int i=0;i<CHUNK;++i){
    unsigned dv = decay[base2 + (size_t)i*256];
    unsigned uv = u[base2 + (size_t)i*256];
    float g0 = blo(dv), g1 = bhi(dv);
    U0 = g0*U0 + blo(uv); G0 *= g0;
    U1 = g1*U1 + bhi(uv); G1 *= g1;
  }
  size_t idx2 = ((size_t)b*NCHUNK + c)*256 + t;
  float2 gv; gv.x=G0; gv.y=G1;
  float2 uv2; uv2.x=U0; uv2.y=U1;
  ((float2*)Gc)[idx2] = gv;
  ((float2*)Uc)[idx2] = uv2;
}

// ---------- merged: b-scan phase 2 (blocks 0-3, batched prefetch) + 'a' scan ----------
__global__ __launch_bounds__(512) void scan2_k(const float* __restrict__ Gc, const float* __restrict__ Uc,
    float* __restrict__ binit, const float* __restrict__ dm, const float* __restrict__ es,
    float* __restrict__ a_out){
  __shared__ float sG[512], sU[512];
  if (blockIdx.x < 4){
    const int b = blockIdx.x, d = threadIdx.x;
    float cur = 0.f;
    for (int c0=0; c0<NCHUNK; c0+=8){
      float g[8], u[8];
      #pragma unroll
      for (int i=0;i<8;++i){
        size_t idx = ((size_t)b*NCHUNK + c0+i)*D_MODEL + d;
        g[i] = Gc[idx]; u[i] = Uc[idx];
      }
      #pragma unroll
      for (int i=0;i<8;++i){
        size_t idx = ((size_t)b*NCHUNK + c0+i)*D_MODEL + d;
        binit[idx] = cur;
        cur = g[i]*cur + u[i];
      }
    }
  } else {
    const int b = blockIdx.x - 4, tid = threadIdx.x;
    const float* dmb = dm + (size_t)b*SEQ;
    const float* esb = es + (size_t)b*SEQ;
    const int t0 = tid*4;
    float gi[4], ui[4];
    #pragma unroll
    for (int i=0;i<4;++i){ gi[i]=dmb[t0+i]; ui[i]=esb[t0+i]; }
    float G=1.f, U=0.f;
    #pragma unroll
    for (int i=0;i<4;++i){ U = gi[i]*U + ui[i]; G *= gi[i]; }
    sG[tid]=G; sU[tid]=U;
    __syncthreads();
    for (int off=1; off<512; off<<=1){
      float pg=1.f, pu=0.f;
      bool act = tid >= off;
      if (act){ pg = sG[tid-off]; pu = sU[tid-off]; }
      __syncthreads();
      if (act){ sU[tid] = sG[tid]*pu + sU[tid]; sG[tid] = sG[tid]*pg; }
      __syncthreads();
    }
    float a = (tid==0) ? 0.f : sU[tid-1];
    #pragma unroll
    for (int i=0;i<4;++i){ a = gi[i]*a + ui[i]; a_out[(size_t)b*SEQ + t0 + i] = a; }
  }
}

// ---------- p3 + LN(merged): one wave per chunk (CHUNK=16), no barriers ----------
__global__ __launch_bounds__(64) void p3ln_k(const uint4* __restrict__ decay,
    const uint4* __restrict__ u,
    const float* __restrict__ binit, const float* __restrict__ a,
    const float* __restrict__ g, const float* __restrict__ be,
    uint4* __restrict__ mb){
  const int c = blockIdx.x, b = blockIdx.y, l = threadIdx.x;
  const size_t rowBase = (size_t)b*SEQ + (size_t)c*CHUNK;   // token row
  float4 bv0 = ((const float4*)binit)[((size_t)b*NCHUNK + c)*128 + l*2];
  float4 bv1 = ((const float4*)binit)[((size_t)b*NCHUNK + c)*128 + l*2 + 1];
  float bv[8] = {bv0.x,bv0.y,bv0.z,bv0.w,bv1.x,bv1.y,bv1.z,bv1.w};
  float4 g0 = ((const float4*)g)[l*2], g1 = ((const float4*)g)[l*2+1];
  float4 b0 = ((const float4*)be)[l*2], b1 = ((const float4*)be)[l*2+1];
  float gv[8] = {g0.x,g0.y,g0.z,g0.w,g1.x,g1.y,g1.z,g1.w};
  float bb[8] = {b0.x,b0.y,b0.z,b0.w,b1.x,b1.y,b1.z,b1.w};
  for (int i=0;i<CHUNK;++i){
    size_t i4 = (rowBase + i)*64 + l;
    uint4 dv = decay[i4], uv = u[i4];
    float dc[8] = {blo(dv.x),bhi(dv.x),blo(dv.y),bhi(dv.y),blo(dv.z),bhi(dv.z),blo(dv.w),bhi(dv.w)};
    float uu[8] = {blo(uv.x),bhi(uv.x),blo(uv.y),bhi(uv.y),blo(uv.z),bhi(uv.z),blo(uv.w),bhi(uv.w)};
    float val[8];
    float av = a[rowBase + i];
    float inv = 1.f/(av + 1e-8f);
    float s1=0.f, s2=0.f;
    #pragma unroll
    for (int k=0;k<8;++k){
      bv[k] = dc[k]*bv[k] + uu[k];
      val[k] = bv[k]*inv;
      s1 += val[k]; s2 += val[k]*val[k];
    }
    wave_red2(s1, s2);
    float mean = s1*(1.f/512.f);
    float var  = s2*(1.f/512.f) - mean*mean;
    float rstd = rsqrtf(var + 1e-5f);
    uint4 mo;
    mo.x = bpack((val[0]-mean)*rstd*gv[0]+bb[0], (val[1]-mean)*rstd*gv[1]+bb[1]);
    mo.y = bpack((val[2]-mean)*rstd*gv[2]+bb[2], (val[3]-mean)*rstd*gv[3]+bb[3]);
    mo.z = bpack((val[4]-mean)*rstd*gv[4]+bb[4], (val[5]-mean)*rstd*gv[5]+bb[5]);
    mo.w = bpack((val[6]-mean)*rstd*gv[6]+bb[6], (val[7]-mean)*rstd*gv[7]+bb[7]);
    mb[i4] = mo;
  }
}

extern "C" void kernel_launch(void* const* d_in, const int* in_sizes, int n_in,
                              void* d_out, int out_size, void* d_ws, size_t ws_size,
                              hipStream_t stream){
  const float* x     = (const float*)d_in[0];
  const float* xp    = (const float*)d_in[1];
  const float* mu    = (const float*)d_in[2];
  const float* in_w  = (const float*)d_in[3];
  const float* in_b  = (const float*)d_in[4];
  const float* out_w = (const float*)d_in[5];
  const float* out_b = (const float*)d_in[6];
  const float* ln1_g = (const float*)d_in[7];
  const float* ln1_b = (const float*)d_in[8];
  const float* tm    = (const float*)d_in[9];
  const float* sm_g  = (const float*)d_in[10];
  const float* sm_b  = (const float*)d_in[11];
  const float* wr_w  = (const float*)d_in[12];
  const float* wr_b  = (const float*)d_in[13];
  const float* wv_w  = (const float*)d_in[14];
  const float* wv_b  = (const float*)d_in[15];
  const float* sc_g  = (const float*)d_in[16];
  const float* sc_b  = (const float*)d_in[17];
  const float* ln2_g = (const float*)d_in[18];
  const float* ln2_b = (const float*)d_in[19];
  const float* w1    = (const float*)d_in[20];
  const float* b1    = (const float*)d_in[21];
  const float* w2    = (const float*)d_in[22];
  const float* b2    = (const float*)d_in[23];
  const float* ln3_g = (const float*)d_in[24];
  const float* ln3_b = (const float*)d_in[25];
  float* out = (float*)d_out;
  float* ws  = (float*)d_ws;

  const size_t N = (size_t)M_TOK*D_MODEL;   // 4,194,304
  unsigned short* P0b = (unsigned short*)ws;            // proj half0 bf16 (8MB)
  unsigned short* X1b = (unsigned short*)ws + N;        // x1 bf16 (8MB)
  unsigned short* F0  = (unsigned short*)(ws + N);      // ffn2 half0 (8MB)
  unsigned short* F1  = (unsigned short*)(ws + N) + N;  // ffn2 half1 (8MB)
  unsigned short* P1b = (unsigned short*)(ws + 2*N);    // proj half1 bf16 (8MB)
  float* EX  = ws + 3*N;
  float* dm    = EX;
  float* es    = EX + 8192;
  float* aarr  = EX + 16384;
  float* Gc    = EX + 24576;
  float* Uc    = Gc + 262144;           // NCHUNK=128: 128*512*4 = 262144 floats
  float* binit = Uc + 262144;

  unsigned short* SB = (unsigned short*)(ws + 3*N + N/4);
  unsigned short* Wq = SB;
  unsigned short* Wo = Wq + 786432;
  unsigned short* Wr = Wo + 262144;
  unsigned short* Wv = Wr + 262144;
  unsigned short* W1 = Wv + 262144;
  unsigned short* W2 = W1 + 1048576;
  unsigned short* Xb = W2 + 1048576;       // shifted bf16, later x2 bf16
  unsigned short* Mb = Xb + N;             // merged bf16
  unsigned short* U  = Mb + N;
  unsigned short* Qb  = U;                 // qkv bf16 (24MB)
  unsigned short* AOb = U + 12*1024*1024;  // attn out bf16 (8MB)
  unsigned short* ub   = U;                // after Qb dead
  unsigned short* decb = U + 12*1024*1024; // after AOb dead
  unsigned short* Rb   = U;                // after ub dead
  unsigned short* Vb   = U + 4*1024*1024;
  unsigned short* Hb   = U;                // FFN hidden (32MB)

  // 0. weight converts + shift (bf16 only)
  cvtshift_k<<<7680, 256, 0, stream>>>(in_w, out_w, wr_w, wv_w, w1, w2,
                                       Wq, Wo, Wr, Wv, W1, W2,
                                       x, xp, mu, Xb);
  // 1. qkv -> Qb
  mgemm_k<0,1><<<dim3(12,64), 256, 0, stream>>>(Xb, Wq, in_b, nullptr, Qb, 1536, 512);
  // 2. flash attention -> AOb
  fattn_k<<<dim3(SEQ/128, NH, BATCH), 512, 0, stream>>>(Qb, AOb);
  // 3. out-proj split-K -> P0b (bias) + P1b
  mgemm64_k<0,0,1><<<dim3(16,64), 256, 0, stream>>>(AOb, Wo, nullptr, out_b, nullptr,
                                                    P0b, P1b, 512, 512);
  // 4. x1 = LN(shifted + P0 + P1) -> X1b; decb/ub; dm/es  (wave-per-row)
  ln_scan_k<<<M_TOK/4, 256, 0, stream>>>((const uint4*)Xb, (const uint4*)P0b,
                                         (const uint4*)P1b,
                                         ln1_g, ln1_b, tm,
                                         (uint4*)X1b, (uint4*)decb, (uint4*)ub,
                                         dm, es);
  // 5. b-scan phase 1 (CHUNK=16, 512 blocks)
  bscan_p1<<<dim3(NCHUNK, BATCH), 256, 0, stream>>>((const unsigned int*)decb, (const unsigned int*)ub, Gc, Uc);
  // 6. merged p2 (batched prefetch) + ascan
  scan2_k<<<8, 512, 0, stream>>>(Gc, Uc, binit, dm, es, aarr);
  // 7. p3 + LN(merged) -> Mb  (one wave per 16-row chunk, 512 waves)
  p3ln_k<<<dim3(NCHUNK, BATCH), 64, 0, stream>>>((const uint4*)decb, (const uint4*)ub,
                                                 binit, aarr, sm_g, sm_b, (uint4*)Mb);
  // 8. r -> Rb, v -> Vb (bf16, fused)
  mgemm64_k<0,1,0><<<dim3(16,64), 256, 0, stream>>>(Mb, Wr, Wv, wr_b, wv_b,
                                                    Rb, Vb, 512, 512);
  // 9. coupled-LN + x2-LN -> Xb (x2 bf16)  (wave-per-row)
  ln2x_k<<<M_TOK/4, 256, 0, stream>>>((const uint4*)Rb, (const uint4*)Vb,
                                      (const uint4*)X1b,
                                      sc_g, sc_b, ln2_g, ln2_b, (uint4*)Xb);
  // 10. hidden = relu(x2 @ w1.T + b1) -> Hb
  mgemm_k<1,1><<<dim3(16,64), 256, 0, stream>>>(Xb, W1, b1, nullptr, Hb, 2048, 512);
  // 11. ffnout split-K -> F0 (bias) + F1
  mgemm64_k<0,0,1><<<dim3(16,64), 256, 0, stream>>>(Hb, W2, nullptr, b2, nullptr,
                                                    F0, F1, 512, 2048);
  // 12. out = LN(x2 + F0 + F1)  (wave-per-row)
  lnfin_k<<<M_TOK/4, 256, 0, stream>>>((const uint4*)Xb, (const uint4*)F0,
                                       (const uint4*)F1, ln3_g, ln3_b, out);
}